// Round 12
// baseline (551.845 us; speedup 1.0000x reference)
//
#include <hip/hip_runtime.h>
#include <math.h>

#define NB 32
#define NG 512
#define NC 384
#define NH 768

typedef float __attribute__((ext_vector_type(2))) f32x2;

// ---------------- GEMM: C = op(A @ Bw + bias). 128x128 tile, 256 threads,
// 8x8 per thread via f32x2 packed FMA. LDS rows padded to 132.
// Software-pipelined staging: loads for tile k+1 issue BEFORE compute(k),
// hiding global latency under ~2000cy of FMA (grid caps residency at 2-3
// blocks/CU, so latency must hide inside the block — round-11 theory).
// K order: k0 += 16, kk ascending -> bit-identical outputs vs rounds 6-11.
// mode 0: relu, mode 1: /0.1 (scores/TAU)
__global__ __launch_bounds__(256, 2) void gemm_bias_128(
    const float* __restrict__ A, const float* __restrict__ Bw,
    const float* __restrict__ bias, float* __restrict__ Co,
    int M, int N, int K, int mode)
{
    __shared__ float sA[16][132];
    __shared__ float sB[16][132];
    int ntiles = N >> 7;
    int bm = (blockIdx.x / ntiles) << 7;
    int bn = (blockIdx.x % ntiles) << 7;
    int t = threadIdx.x;
    int tx = t & 15, ty = t >> 4;
    int tr = t >> 2, tc = t & 3;
    const float* Aptr0 = A + (size_t)(bm + tr) * K + 4 * tc;
    const float* Aptr1 = A + (size_t)(bm + 64 + tr) * K + 4 * tc;
    int kb = t >> 4, nc = t & 15;
    const float* BptrL = Bw + (size_t)kb * N + bn + 4 * nc;
    const float* BptrH = Bw + (size_t)kb * N + bn + 64 + 4 * nc;

    f32x2 acc2[8][4];
#pragma unroll
    for (int i = 0; i < 8; i++)
#pragma unroll
        for (int j = 0; j < 4; j++) acc2[i][j] = (f32x2)(0.f);

    // prefetch tile 0
    float4 a0 = *(const float4*)(Aptr0);
    float4 a1 = *(const float4*)(Aptr1);
    float4 b0 = *(const float4*)(BptrL);
    float4 b1 = *(const float4*)(BptrH);

    for (int k0 = 0; k0 < K; k0 += 16) {
        __syncthreads();          // all waves done computing previous tile
        sA[4 * tc + 0][tr] = a0.x;
        sA[4 * tc + 1][tr] = a0.y;
        sA[4 * tc + 2][tr] = a0.z;
        sA[4 * tc + 3][tr] = a0.w;
        sA[4 * tc + 0][64 + tr] = a1.x;
        sA[4 * tc + 1][64 + tr] = a1.y;
        sA[4 * tc + 2][64 + tr] = a1.z;
        sA[4 * tc + 3][64 + tr] = a1.w;
        *(float4*)&sB[kb][4 * nc] = b0;
        *(float4*)&sB[kb][64 + 4 * nc] = b1;
        __syncthreads();          // LDS ready
        // issue next tile's loads now; latency hides under the FMA block
        if (k0 + 16 < K) {
            a0 = *(const float4*)(Aptr0 + k0 + 16);
            a1 = *(const float4*)(Aptr1 + k0 + 16);
            b0 = *(const float4*)(BptrL + (size_t)(k0 + 16) * N);
            b1 = *(const float4*)(BptrH + (size_t)(k0 + 16) * N);
        }
#pragma unroll
        for (int kk = 0; kk < 16; kk++) {
            float4 aL = *(const float4*)&sA[kk][4 * ty];
            float4 aH = *(const float4*)&sA[kk][64 + 4 * ty];
            float4 bL = *(const float4*)&sB[kk][4 * tx];
            float4 bH = *(const float4*)&sB[kk][64 + 4 * tx];
            float av[8] = { aL.x, aL.y, aL.z, aL.w, aH.x, aH.y, aH.z, aH.w };
            f32x2 bb[4];
            bb[0].x = bL.x; bb[0].y = bL.y;
            bb[1].x = bL.z; bb[1].y = bL.w;
            bb[2].x = bH.x; bb[2].y = bH.y;
            bb[3].x = bH.z; bb[3].y = bH.w;
#pragma unroll
            for (int i = 0; i < 8; i++) {
                f32x2 aa; aa.x = av[i]; aa.y = av[i];
#pragma unroll
                for (int j = 0; j < 4; j++)
                    acc2[i][j] = __builtin_elementwise_fma(aa, bb[j], acc2[i][j]);
            }
        }
    }

    float4 blo = *(const float4*)(bias + bn + 4 * tx);
    float4 bhi = *(const float4*)(bias + bn + 64 + 4 * tx);
    float bb8[8] = { blo.x, blo.y, blo.z, blo.w, bhi.x, bhi.y, bhi.z, bhi.w };
#pragma unroll
    for (int i = 0; i < 8; i++) {
        int row = bm + ((i < 4) ? (4 * ty + i) : (64 + 4 * ty + i - 4));
        float vals[8];
        vals[0] = acc2[i][0].x + bb8[0];
        vals[1] = acc2[i][0].y + bb8[1];
        vals[2] = acc2[i][1].x + bb8[2];
        vals[3] = acc2[i][1].y + bb8[3];
        vals[4] = acc2[i][2].x + bb8[4];
        vals[5] = acc2[i][2].y + bb8[5];
        vals[6] = acc2[i][3].x + bb8[6];
        vals[7] = acc2[i][3].y + bb8[7];
#pragma unroll
        for (int j = 0; j < 8; j++)
            vals[j] = (mode == 0) ? fmaxf(vals[j], 0.f) : vals[j] / 0.1f;
        float4 oL; oL.x = vals[0]; oL.y = vals[1]; oL.z = vals[2]; oL.w = vals[3];
        float4 oH; oH.x = vals[4]; oH.y = vals[5]; oH.z = vals[6]; oH.w = vals[7];
        *(float4*)(Co + (size_t)row * N + bn + 4 * tx) = oL;
        *(float4*)(Co + (size_t)row * N + bn + 64 + 4 * tx) = oH;
    }
}

// ======== DPP reduce networks to lane 63 (pure VALU) ========
#define DPP6_MAXF(x)                                                              \
    { int _t;                                                                     \
      _t = __builtin_amdgcn_update_dpp(__float_as_int(x), __float_as_int(x),      \
               0x111, 0xf, 0xf, false); x = fmaxf(x, __int_as_float(_t));         \
      _t = __builtin_amdgcn_update_dpp(__float_as_int(x), __float_as_int(x),      \
               0x112, 0xf, 0xf, false); x = fmaxf(x, __int_as_float(_t));         \
      _t = __builtin_amdgcn_update_dpp(__float_as_int(x), __float_as_int(x),      \
               0x114, 0xf, 0xf, false); x = fmaxf(x, __int_as_float(_t));         \
      _t = __builtin_amdgcn_update_dpp(__float_as_int(x), __float_as_int(x),      \
               0x118, 0xf, 0xf, false); x = fmaxf(x, __int_as_float(_t));         \
      _t = __builtin_amdgcn_update_dpp(__float_as_int(x), __float_as_int(x),      \
               0x142, 0xa, 0xf, false); x = fmaxf(x, __int_as_float(_t));         \
      _t = __builtin_amdgcn_update_dpp(__float_as_int(x), __float_as_int(x),      \
               0x143, 0xc, 0xf, false); x = fmaxf(x, __int_as_float(_t)); }

#define DPP6_ADDF(x)                                                              \
    { int _t;                                                                     \
      _t = __builtin_amdgcn_update_dpp(__float_as_int(x), __float_as_int(x),      \
               0x111, 0xf, 0xf, false); x = x + __int_as_float(_t);               \
      _t = __builtin_amdgcn_update_dpp(__float_as_int(x), __float_as_int(x),      \
               0x112, 0xf, 0xf, false); x = x + __int_as_float(_t);               \
      _t = __builtin_amdgcn_update_dpp(__float_as_int(x), __float_as_int(x),      \
               0x114, 0xf, 0xf, false); x = x + __int_as_float(_t);               \
      _t = __builtin_amdgcn_update_dpp(__float_as_int(x), __float_as_int(x),      \
               0x118, 0xf, 0xf, false); x = x + __int_as_float(_t);               \
      _t = __builtin_amdgcn_update_dpp(__float_as_int(x), __float_as_int(x),      \
               0x142, 0xa, 0xf, false); x = x + __int_as_float(_t);               \
      _t = __builtin_amdgcn_update_dpp(__float_as_int(x), __float_as_int(x),      \
               0x143, 0xc, 0xf, false); x = x + __int_as_float(_t); }

// ---------------- Fused Sinkhorn half-iterations (see round-9 notes).
__global__ __launch_bounds__(256) void sinkhorn_iter(
    const float* __restrict__ A0, float* __restrict__ uu,
    const float* __restrict__ vv, float* __restrict__ ps)
{
    int blk = blockIdx.x;          // NB*8
    int b = blk >> 3, rc = blk & 7;
    int t = threadIdx.x;
    int l = t & 63, w = t >> 6;
    const float* vb = vv + (b << 9);
    float4 v0 = *(const float4*)(vb + 4 * l);
    float4 v1 = *(const float4*)(vb + 256 + 4 * l);
    int row0 = (rc << 6) + (w << 4);
    const float* base = A0 + ((size_t)((b << 9) + row0) << 9);

    float cs0 = 0.f, cs1 = 0.f, cs2 = 0.f, cs3 = 0.f;
    float cs4 = 0.f, cs5 = 0.f, cs6 = 0.f, cs7 = 0.f;

    for (int rr = 0; rr < 16; ++rr) {
        const float* rowp = base + ((size_t)rr << 9);
        float4 a0 = *(const float4*)(rowp + 4 * l);
        float4 a1 = *(const float4*)(rowp + 256 + 4 * l);
        float x0 = a0.x + v0.x, x1 = a0.y + v0.y;
        float x2 = a0.z + v0.z, x3 = a0.w + v0.w;
        float x4 = a1.x + v1.x, x5 = a1.y + v1.y;
        float x6 = a1.z + v1.z, x7 = a1.w + v1.w;
        float m = fmaxf(fmaxf(fmaxf(x0, x1), fmaxf(x2, x3)),
                        fmaxf(fmaxf(x4, x5), fmaxf(x6, x7)));
        DPP6_MAXF(m)
        int mi = __builtin_amdgcn_readlane(__float_as_int(m), 63);
        m = __int_as_float(mi);
        float e0 = __expf(x0 - m), e1 = __expf(x1 - m);
        float e2 = __expf(x2 - m), e3 = __expf(x3 - m);
        float e4 = __expf(x4 - m), e5 = __expf(x5 - m);
        float e6 = __expf(x6 - m), e7 = __expf(x7 - m);
        float s = ((e0 + e1) + (e2 + e3)) + ((e4 + e5) + (e6 + e7));
        DPP6_ADDF(s)
        int si = __builtin_amdgcn_readlane(__float_as_int(s), 63);
        s = __int_as_float(si);
        float inv = 1.0f / s;
        cs0 += e0 * inv; cs1 += e1 * inv; cs2 += e2 * inv; cs3 += e3 * inv;
        cs4 += e4 * inv; cs5 += e5 * inv; cs6 += e6 * inv; cs7 += e7 * inv;
        if (l == 63) uu[(b << 9) + row0 + rr] = -(m + __logf(s));
    }

    __shared__ float sacc[4][512];
    float4 w0; w0.x = cs0; w0.y = cs1; w0.z = cs2; w0.w = cs3;
    float4 w1; w1.x = cs4; w1.y = cs5; w1.z = cs6; w1.w = cs7;
    *(float4*)&sacc[w][4 * l] = w0;
    *(float4*)&sacc[w][256 + 4 * l] = w1;
    __syncthreads();
    float pA = sacc[0][t] + sacc[1][t] + sacc[2][t] + sacc[3][t];
    float pB = sacc[0][256 + t] + sacc[1][256 + t] + sacc[2][256 + t] + sacc[3][256 + t];
    int o = ((b << 3) + rc) * NG;
    ps[o + t] = pA;
    ps[o + 256 + t] = pB;
}

// ---------------- combine 8 linear partials -> v' = v - log(colsum)
__global__ __launch_bounds__(256) void col_combine_lin(
    const float* __restrict__ ps, float* __restrict__ vv)
{
    int tid = blockIdx.x * 256 + threadIdx.x;  // NB*NG
    int b = tid >> 9, j = tid & 511;
    float S = 0.f;
#pragma unroll
    for (int rc = 0; rc < 8; rc++) S += ps[((b << 3) + rc) * NG + j];
    vv[tid] = vv[tid] - __logf(S);
}

// wave-cooperative masked row argmax over cols 8l..8l+7 per lane.
__device__ __forceinline__ void masked_row_argmax(
    const float* __restrict__ rowp, int l, unsigned int free8, int rr,
    float& outV, int& outF)
{
    float4 x0 = *(const float4*)(rowp + 8 * l);
    float4 x1 = *(const float4*)(rowp + 8 * l + 4);
    float q0 = (free8 & 1u)   ? x0.x : -1.0f;
    float q1 = (free8 & 2u)   ? x0.y : -1.0f;
    float q2 = (free8 & 4u)   ? x0.z : -1.0f;
    float q3 = (free8 & 8u)   ? x0.w : -1.0f;
    float q4 = (free8 & 16u)  ? x1.x : -1.0f;
    float q5 = (free8 & 32u)  ? x1.y : -1.0f;
    float q6 = (free8 & 64u)  ? x1.z : -1.0f;
    float q7 = (free8 & 128u) ? x1.w : -1.0f;
    float lm = fmaxf(fmaxf(fmaxf(q0, q1), fmaxf(q2, q3)),
                     fmaxf(fmaxf(q4, q5), fmaxf(q6, q7)));
    int sb = (rr << 9) + 8 * l;
    int lf = 0x7FFFFFFF;
    lf = (q7 == lm) ? sb + 7 : lf;
    lf = (q6 == lm) ? sb + 6 : lf;
    lf = (q5 == lm) ? sb + 5 : lf;
    lf = (q4 == lm) ? sb + 4 : lf;
    lf = (q3 == lm) ? sb + 3 : lf;
    lf = (q2 == lm) ? sb + 2 : lf;
    lf = (q1 == lm) ? sb + 1 : lf;
    lf = (q0 == lm) ? sb + 0 : lf;
    float gg = lm;
    DPP6_MAXF(gg)
    int ggi = __builtin_amdgcn_readlane(__float_as_int(gg), 63);
    float g1 = __int_as_float(ggi);
    unsigned long long tb = __ballot(lm == g1);
    int tl = __ffsll(tb) - 1;
    outV = g1;
    outF = __builtin_amdgcn_readlane(lf, tl);
}

// ---------------- P = exp((A0+u)+v) (libm expf) + per-row argmax + state init.
__global__ __launch_bounds__(256) void p_rowmax(
    const float* __restrict__ A0, const float* __restrict__ uu,
    const float* __restrict__ vv, float* __restrict__ P,
    int* __restrict__ rbCr, int* __restrict__ rbCc,
    unsigned long long* __restrict__ freeRow,
    unsigned long long* __restrict__ freeCol,
    int* __restrict__ remaining)
{
    if (blockIdx.x == 0) {
        int t = threadIdx.x;
        freeRow[t] = ~0ULL;
        freeCol[t] = ~0ULL;
        if (t < NB) remaining[t] = NG;
    }
    int wrow = blockIdx.x * 4 + (threadIdx.x >> 6);
    int l = threadIdx.x & 63;
    int b = wrow >> 9;
    float ur = uu[wrow];
    const float* vb = vv + (b << 9);
    size_t ro = (size_t)wrow << 9;
    float4 a0 = *(const float4*)(A0 + ro + 8 * l);
    float4 a1 = *(const float4*)(A0 + ro + 8 * l + 4);
    float4 v0 = *(const float4*)(vb + 8 * l);
    float4 v1 = *(const float4*)(vb + 8 * l + 4);
    float p0 = expf(a0.x + ur + v0.x);
    float p1 = expf(a0.y + ur + v0.y);
    float p2 = expf(a0.z + ur + v0.z);
    float p3 = expf(a0.w + ur + v0.w);
    float p4 = expf(a1.x + ur + v1.x);
    float p5 = expf(a1.y + ur + v1.y);
    float p6 = expf(a1.z + ur + v1.z);
    float p7 = expf(a1.w + ur + v1.w);
    float4 o0; o0.x = p0; o0.y = p1; o0.z = p2; o0.w = p3;
    float4 o1; o1.x = p4; o1.y = p5; o1.z = p6; o1.w = p7;
    *(float4*)(P + ro + 8 * l) = o0;
    *(float4*)(P + ro + 8 * l + 4) = o1;
    float mv = fmaxf(fmaxf(fmaxf(p0, p1), fmaxf(p2, p3)),
                     fmaxf(fmaxf(p4, p5), fmaxf(p6, p7)));
    int cb = 8 * l;
    int f = 0x7FFFFFFF;
    f = (p7 == mv) ? cb + 7 : f;
    f = (p6 == mv) ? cb + 6 : f;
    f = (p5 == mv) ? cb + 5 : f;
    f = (p4 == mv) ? cb + 4 : f;
    f = (p3 == mv) ? cb + 3 : f;
    f = (p2 == mv) ? cb + 2 : f;
    f = (p1 == mv) ? cb + 1 : f;
    f = (p0 == mv) ? cb + 0 : f;
    float g = mv;
    DPP6_MAXF(g)
    int gi = __builtin_amdgcn_readlane(__float_as_int(g), 63);
    float gm = __int_as_float(gi);
    unsigned long long tb = __ballot(mv == gm);
    int tl = __ffsll(tb) - 1;
    int bestc = __builtin_amdgcn_readlane(f, tl);
    if (l == 0) { rbCr[wrow] = bestc; rbCc[wrow] = -1; }
}

// ---------------- One parallel mutual-max round (exact greedy equivalence).
__global__ __launch_bounds__(512) void mutual_round(
    const float* __restrict__ P, int* __restrict__ rbCr, int* __restrict__ rbCc,
    unsigned long long* __restrict__ freeRow,
    unsigned long long* __restrict__ freeCol,
    int* __restrict__ remaining, int* __restrict__ permInt)
{
    int b = blockIdx.x;
    if (remaining[b] == 0) return;
    int t = threadIdx.x;
    int l = t & 63;
    int w = t >> 6;
    const float* Pb = P + (size_t)b * NG * NG;

    __shared__ unsigned int fr[16], fc[16];
    __shared__ int sRC[NG];
    __shared__ int sCC[NG];
    __shared__ int freeList[NG];
    __shared__ int dirtyRows[NG];
    __shared__ int nFree, nDirtyRow, takeCnt;
    __shared__ int wCnt[8], wOff[8];

    if (t < 8) {
        unsigned long long x = freeRow[b * 8 + t];
        fr[2 * t] = (unsigned)x; fr[2 * t + 1] = (unsigned)(x >> 32);
    } else if (t < 16) {
        int i = t - 8;
        unsigned long long x = freeCol[b * 8 + i];
        fc[2 * i] = (unsigned)x; fc[2 * i + 1] = (unsigned)(x >> 32);
    }
    sRC[t] = rbCr[(b << 9) + t];
    sCC[t] = rbCc[(b << 9) + t];
    if (t == 0) { nDirtyRow = 0; takeCnt = 0; }
    __syncthreads();

    bool isFree = (fr[t >> 5] >> (t & 31)) & 1u;
    unsigned long long bm = __ballot(isFree);
    if (l == 0) wCnt[w] = __popcll(bm);
    if (isFree) {
        int c = sRC[t];
        if (!((fc[c >> 5] >> (c & 31)) & 1u)) {
            int d = atomicAdd(&nDirtyRow, 1);
            dirtyRows[d] = t;
        }
    }
    __syncthreads();
    if (t == 0) {
        int s = 0;
#pragma unroll
        for (int i = 0; i < 8; i++) { wOff[i] = s; s += wCnt[i]; }
        nFree = s;
    }
    __syncthreads();
    if (isFree) {
        int rank = __popcll(bm & ((1ULL << l) - 1ULL));
        freeList[wOff[w] + rank] = t;
    }
    __syncthreads();

    int nd = nDirtyRow;
    for (int d = w; d < nd; d += 8) {
        int r = dirtyRows[d];
        unsigned int free8 = (fc[l >> 2] >> ((l & 3) * 8)) & 0xFFu;
        float nv; int nf;
        masked_row_argmax(Pb + ((size_t)r << 9), l, free8, r, nv, nf);
        if (l == 0) {
            int c = nf & 511;
            sRC[r] = c;
            rbCr[(b << 9) + r] = c;
        }
    }
    __syncthreads();

    bool colFree = (fc[t >> 5] >> (t & 31)) & 1u;
    int cachedR = sCC[t];
    bool colDirty = colFree &&
        (cachedR < 0 || !((fr[cachedR >> 5] >> (cachedR & 31)) & 1u));
    if (colDirty) {
        float best = -1.f; int bestr = 0x7FFFFFFF;
        int nf2 = nFree;
        int i = 0;
        for (; i + 4 <= nf2; i += 4) {
            int r0 = freeList[i], r1 = freeList[i + 1];
            int r2 = freeList[i + 2], r3 = freeList[i + 3];
            float v0 = Pb[((size_t)r0 << 9) + t];
            float v1 = Pb[((size_t)r1 << 9) + t];
            float v2 = Pb[((size_t)r2 << 9) + t];
            float v3 = Pb[((size_t)r3 << 9) + t];
            if (v0 > best) { best = v0; bestr = r0; }
            if (v1 > best) { best = v1; bestr = r1; }
            if (v2 > best) { best = v2; bestr = r2; }
            if (v3 > best) { best = v3; bestr = r3; }
        }
        for (; i < nf2; ++i) {
            int ri = freeList[i];
            float vv2 = Pb[((size_t)ri << 9) + t];
            if (vv2 > best) { best = vv2; bestr = ri; }
        }
        sCC[t] = bestr;
        rbCc[(b << 9) + t] = bestr;
    }
    __syncthreads();

    if (colFree) {
        int r = sCC[t];
        if (r >= 0 && r < NG && sRC[r] == t) {
            permInt[(b << 9) + r] = t;
            atomicAnd(&fr[r >> 5], ~(1u << (r & 31)));
            atomicAnd(&fc[t >> 5], ~(1u << (t & 31)));
            atomicAdd(&takeCnt, 1);
        }
    }
    __syncthreads();
    if (t < 8) {
        freeRow[b * 8 + t] =
            ((unsigned long long)fr[2 * t + 1] << 32) | fr[2 * t];
    } else if (t < 16) {
        int i = t - 8;
        freeCol[b * 8 + i] =
            ((unsigned long long)fc[2 * i + 1] << 32) | fc[2 * i];
    }
    if (t == 0) remaining[b] = remaining[b] - takeCnt;
}

// ---------------- Exact sequential cleanup (rarely does work).
__global__ __launch_bounds__(64) void greedy_cleanup(
    const float* __restrict__ P,
    const unsigned long long* __restrict__ freeRow,
    const unsigned long long* __restrict__ freeCol,
    const int* __restrict__ remaining, int* __restrict__ permInt)
{
    int b = blockIdx.x;
    if (remaining[b] == 0) return;
    int l = threadIdx.x;
    const float* Pb = P + (size_t)b * NG * NG;

    unsigned long long wR = freeRow[b * 8 + (l >> 3)];
    unsigned int myRows = (unsigned int)((wR >> ((l & 7) * 8)) & 0xFF);
    unsigned long long wC = freeCol[b * 8 + (l >> 3)];
    unsigned int free8 = (unsigned int)((wC >> ((l & 7) * 8)) & 0xFF);

    float rv[8]; int rf[8];
#pragma unroll
    for (int k = 0; k < 8; k++) { rv[k] = -1.f; rf[k] = 0x7FFFFFFF; }

    int dmk = (int)myRows;
    unsigned long long act = __ballot(dmk != 0);
    while (act) {
        int src = __ffsll(act) - 1;
        int kk = __ffs(__builtin_amdgcn_readlane(dmk, src)) - 1;
        if (l == src) dmk &= ~(1 << kk);
        int rr = (src << 3) + kk;
        float nv; int nf;
        masked_row_argmax(Pb + ((size_t)rr << 9), l, free8, rr, nv, nf);
        bool upd = (l == src);
        rv[0] = (upd && kk == 0) ? nv : rv[0]; rf[0] = (upd && kk == 0) ? nf : rf[0];
        rv[1] = (upd && kk == 1) ? nv : rv[1]; rf[1] = (upd && kk == 1) ? nf : rf[1];
        rv[2] = (upd && kk == 2) ? nv : rv[2]; rf[2] = (upd && kk == 2) ? nf : rf[2];
        rv[3] = (upd && kk == 3) ? nv : rv[3]; rf[3] = (upd && kk == 3) ? nf : rf[3];
        rv[4] = (upd && kk == 4) ? nv : rv[4]; rf[4] = (upd && kk == 4) ? nf : rf[4];
        rv[5] = (upd && kk == 5) ? nv : rv[5]; rf[5] = (upd && kk == 5) ? nf : rf[5];
        rv[6] = (upd && kk == 6) ? nv : rv[6]; rf[6] = (upd && kk == 6) ? nf : rf[6];
        rv[7] = (upd && kk == 7) ? nv : rv[7]; rf[7] = (upd && kk == 7) ? nf : rf[7];
        act = __ballot(dmk != 0);
    }

    for (int step = 0; step < NG; ++step) {
        float mv = fmaxf(fmaxf(fmaxf(rv[0], rv[1]), fmaxf(rv[2], rv[3])),
                         fmaxf(fmaxf(rv[4], rv[5]), fmaxf(rv[6], rv[7])));
        int f = 0x7FFFFFFF;
        f = (rv[7] == mv) ? rf[7] : f;
        f = (rv[6] == mv) ? rf[6] : f;
        f = (rv[5] == mv) ? rf[5] : f;
        f = (rv[4] == mv) ? rf[4] : f;
        f = (rv[3] == mv) ? rf[3] : f;
        f = (rv[2] == mv) ? rf[2] : f;
        f = (rv[1] == mv) ? rf[1] : f;
        f = (rv[0] == mv) ? rf[0] : f;
        float g = mv;
        DPP6_MAXF(g)
        int gi = __builtin_amdgcn_readlane(__float_as_int(g), 63);
        float gm = __int_as_float(gi);
        if (gm < 0.f) break;
        unsigned long long tb = __ballot(mv == gm);
        int tl = __ffsll(tb) - 1;
        int bestf = __builtin_amdgcn_readlane(f, tl);
        int r = bestf >> 9, c = bestf & 511;
        if (l == 0) permInt[(b << 9) + r] = c;
        if (l == (c >> 3)) free8 &= ~(1u << (c & 7));
        int rl = r - (l << 3);
        int dm2 = 0;
#pragma unroll
        for (int k = 0; k < 8; k++) {
            bool alive = rv[k] >= 0.f;
            bool cm = ((rf[k] ^ c) & 511) == 0;
            bool taken = (rl == k);
            if (taken) rv[k] = -1.f;
            dm2 |= (alive && cm && !taken) ? (1 << k) : 0;
        }
        unsigned long long act2 = __ballot(dm2 != 0);
        while (act2) {
            int src = __ffsll(act2) - 1;
            int kk = __ffs(__builtin_amdgcn_readlane(dm2, src)) - 1;
            if (l == src) dm2 &= ~(1 << kk);
            int rr = (src << 3) + kk;
            float nv; int nf;
            masked_row_argmax(Pb + ((size_t)rr << 9), l, free8, rr, nv, nf);
            bool upd = (l == src);
            rv[0] = (upd && kk == 0) ? nv : rv[0]; rf[0] = (upd && kk == 0) ? nf : rf[0];
            rv[1] = (upd && kk == 1) ? nv : rv[1]; rf[1] = (upd && kk == 1) ? nf : rf[1];
            rv[2] = (upd && kk == 2) ? nv : rv[2]; rf[2] = (upd && kk == 2) ? nf : rf[2];
            rv[3] = (upd && kk == 3) ? nv : rv[3]; rf[3] = (upd && kk == 3) ? nf : rf[3];
            rv[4] = (upd && kk == 4) ? nv : rv[4]; rf[4] = (upd && kk == 4) ? nf : rf[4];
            rv[5] = (upd && kk == 5) ? nv : rv[5]; rf[5] = (upd && kk == 5) ? nf : rf[5];
            rv[6] = (upd && kk == 6) ? nv : rv[6]; rf[6] = (upd && kk == 6) ? nf : rf[6];
            rv[7] = (upd && kk == 7) ? nv : rv[7]; rf[7] = (upd && kk == 7) ? nf : rf[7];
            act2 = __ballot(dm2 != 0);
        }
    }
}

// ---------------- apply permutation (coords + feats + perm float, fused)
__global__ void scatter_all(const float* __restrict__ coords,
    const float* __restrict__ feats, const int* __restrict__ perm,
    float* __restrict__ dstCoords, float* __restrict__ dstFeats,
    float* __restrict__ permF)
{
    int tid = blockIdx.x * 256 + threadIdx.x;   // NB*NG*96 float4s
    int rc = tid / 96;
    int q = tid - rc * 96;
    int b = rc >> 9;
    int p = perm[rc];
    const float4* s4 = (const float4*)(feats + (size_t)rc * NC);
    float4* d4 = (float4*)(dstFeats + ((size_t)(b << 9) + p) * NC);
    d4[q] = s4[q];
    if (q == 0) {
        permF[rc] = (float)p;
        size_t so = (size_t)rc * 3;
        size_t dd = ((size_t)(b << 9) + p) * 3;
        dstCoords[dd] = coords[so];
        dstCoords[dd + 1] = coords[so + 1];
        dstCoords[dd + 2] = coords[so + 2];
    }
}

extern "C" void kernel_launch(void* const* d_in, const int* in_sizes, int n_in,
                              void* d_out, int out_size, void* d_ws, size_t ws_size,
                              hipStream_t stream)
{
    const float* coords = (const float*)d_in[0];
    const float* feats  = (const float*)d_in[1];
    const float* W1 = (const float*)d_in[2];
    const float* b1 = (const float*)d_in[3];
    const float* W2 = (const float*)d_in[4];
    const float* b2 = (const float*)d_in[5];

    float* out = (float*)d_out;
    float* outCoords = out;
    float* outFeats  = out + (size_t)NB * NG * 3;
    float* outPerm   = out + (size_t)NB * NG * 3 + (size_t)NB * NG * NC;

    float* ws = (float*)d_ws;
    float* h   = ws;                                  // 16384*768 (reused as P)
    float* A0  = h + (size_t)NB * NG * NH;            // 16384*512
    float* u   = A0 + (size_t)NB * NG * NG;           // 16384
    float* v   = u + NB * NG;                         // 16384
    float* pm  = v + NB * NG;                         // 32*8*512 (unused)
    float* ps  = pm + NB * 8 * NG;                    // 32*8*512
    int* rbCr  = (int*)(ps + NB * 8 * NG);            // 16384
    int* rbCc  = rbCr + NB * NG;                      // 16384
    unsigned long long* freeRow = (unsigned long long*)(rbCc + NB * NG); // 256
    unsigned long long* freeCol = freeRow + NB * 8;   // 256
    int* remaining = (int*)(freeCol + NB * 8);        // 32
    int* permInt   = remaining + 32;                  // 16384

    const int M = NB * NG;  // 16384

    // h = relu(feats @ W1 + b1)
    gemm_bias_128<<<dim3((M / 128) * (NH / 128)), 256, 0, stream>>>(
        feats, W1, b1, h, M, NH, NC, 0);
    // A0 = (h @ W2 + b2) / TAU
    gemm_bias_128<<<dim3((M / 128) * (NG / 128)), 256, 0, stream>>>(
        h, W2, b2, A0, M, NG, NH, 1);

    hipMemsetAsync(v, 0, (size_t)NB * NG * sizeof(float), stream);

    for (int it = 0; it < 10; ++it) {
        sinkhorn_iter<<<dim3(NB * 8), 256, 0, stream>>>(A0, u, v, ps);
        col_combine_lin<<<dim3(M / 256), 256, 0, stream>>>(ps, v);
    }

    float* P = h;
    p_rowmax<<<dim3(M / 4), 256, 0, stream>>>(A0, u, v, P, rbCr, rbCc,
                                              freeRow, freeCol, remaining);

    for (int r = 0; r < 6; ++r)
        mutual_round<<<dim3(NB), 512, 0, stream>>>(P, rbCr, rbCc, freeRow,
                                                   freeCol, remaining, permInt);

    greedy_cleanup<<<dim3(NB), 64, 0, stream>>>(P, freeRow, freeCol,
                                                remaining, permInt);

    scatter_all<<<dim3((NB * NG * 96) / 256), 256, 0, stream>>>(
        coords, feats, permInt, outCoords, outFeats, outPerm);
}

// Round 13
// 422.364 us; speedup vs baseline: 1.3066x; 1.3066x over previous
//
#include <hip/hip_runtime.h>
#include <math.h>

#define NB 32
#define NG 512
#define NC 384
#define NH 768

typedef float f32x4v __attribute__((ext_vector_type(4)));
typedef __bf16 bf16_t;
typedef bf16_t bf16x8 __attribute__((ext_vector_type(8)));
typedef bf16_t bf16x4 __attribute__((ext_vector_type(4)));

#define LDSK 40   // 32 k (permuted) + 8 pad; row stride 80 B (16B-aligned)

__device__ __forceinline__ void split3(float x, bf16_t& h, bf16_t& m, bf16_t& lo)
{
    h = (bf16_t)x;
    float r1 = x - (float)h;
    m = (bf16_t)r1;
    float r2 = r1 - (float)m;
    lo = (bf16_t)r2;
}

// ---------------- GEMM via bf16 MFMA, exact 3-way split (8 products; dropped
// l*l ~ 2^-32 => error in the fp32-reorder-noise class). 128x128 tile, 4 waves
// (2x2 of 64x64), K-chunk 32. LDS k-dim stored PERMUTED so each MFMA fragment
// (k = (l>>4)*4 + (j&3) + 16*(j>>2)) is one contiguous ds_read_b128:
// pos(k) = ((k>>2)&3)*8 + (k>>4)*4 + (k&3).
// mode 0: relu, mode 1: /0.1 (scores/TAU). Deterministic fixed order.
__global__ __launch_bounds__(256, 2) void gemm_bias_mfma(
    const float* __restrict__ A, const float* __restrict__ Bw,
    const float* __restrict__ bias, float* __restrict__ Co,
    int M, int N, int K, int mode)
{
    __shared__ __align__(16) bf16_t sA[3][128][LDSK];
    __shared__ __align__(16) bf16_t sB[3][128][LDSK];   // B^T: [col][k-pos]
    int ntiles = N >> 7;
    int bm = (blockIdx.x / ntiles) << 7;
    int bn = (blockIdx.x % ntiles) << 7;
    int t = threadIdx.x;
    int l = t & 63;
    int w = t >> 6;
    int wr = (w >> 1) << 6;       // wave row base (0/64)
    int wc = (w & 1) << 6;        // wave col base (0/64)
    int fr = l & 15;              // frag row/col
    int fk = (l >> 4) << 3;       // frag k-pos base (0,8,16,24)

    // staging: A: thread -> (row = t>>1, khalf = (t&1)*16)
    int sa_row = t >> 1;
    int sa_kh = (t & 1) << 4;
    int hsel = (sa_kh >> 4) << 2;      // 0 or 4
    // staging: B: thread -> (k quad = (t&7)*4, col quad = (t>>3)*4)
    int sb_k = (t & 7) << 2;
    int sb_n = (t >> 3) << 2;
    int bcol = ((sb_k >> 2) & 3) * 8 + ((sb_k >> 4) << 2);

    f32x4v acc[4][4];
#pragma unroll
    for (int i = 0; i < 4; i++)
#pragma unroll
        for (int j = 0; j < 4; j++) acc[i][j] = (f32x4v)(0.f);

    for (int kc = 0; kc < K; kc += 32) {
        __syncthreads();
        // ---- stage A (128x32 fp32 -> 3 bf16 splits, k-permuted) ----
        {
            const float* ap = A + (size_t)(bm + sa_row) * K + kc + sa_kh;
            float4 q0 = *(const float4*)(ap + 0);
            float4 q1 = *(const float4*)(ap + 4);
            float4 q2 = *(const float4*)(ap + 8);
            float4 q3 = *(const float4*)(ap + 12);
            float xs[16] = { q0.x, q0.y, q0.z, q0.w, q1.x, q1.y, q1.z, q1.w,
                             q2.x, q2.y, q2.z, q2.w, q3.x, q3.y, q3.z, q3.w };
            bf16_t hs[16], ms[16], ls[16];
#pragma unroll
            for (int e = 0; e < 16; e++) split3(xs[e], hs[e], ms[e], ls[e]);
#pragma unroll
            for (int qd = 0; qd < 4; qd++) {
                int col = qd * 8 + hsel;
                *(bf16x4*)&sA[0][sa_row][col] =
                    (bf16x4){ hs[4 * qd], hs[4 * qd + 1], hs[4 * qd + 2], hs[4 * qd + 3] };
                *(bf16x4*)&sA[1][sa_row][col] =
                    (bf16x4){ ms[4 * qd], ms[4 * qd + 1], ms[4 * qd + 2], ms[4 * qd + 3] };
                *(bf16x4*)&sA[2][sa_row][col] =
                    (bf16x4){ ls[4 * qd], ls[4 * qd + 1], ls[4 * qd + 2], ls[4 * qd + 3] };
            }
        }
        // ---- stage B (32x128 fp32 -> B^T 3 bf16 splits, k-permuted) ----
        {
            float bbv[4][4];
#pragma unroll
            for (int kk = 0; kk < 4; kk++) {
                float4 bq = *(const float4*)(Bw + (size_t)(kc + sb_k + kk) * N + bn + sb_n);
                bbv[kk][0] = bq.x; bbv[kk][1] = bq.y; bbv[kk][2] = bq.z; bbv[kk][3] = bq.w;
            }
#pragma unroll
            for (int n = 0; n < 4; n++) {
                bf16_t hb[4], mb[4], lb[4];
#pragma unroll
                for (int kk = 0; kk < 4; kk++) split3(bbv[kk][n], hb[kk], mb[kk], lb[kk]);
                *(bf16x4*)&sB[0][sb_n + n][bcol] = (bf16x4){ hb[0], hb[1], hb[2], hb[3] };
                *(bf16x4*)&sB[1][sb_n + n][bcol] = (bf16x4){ mb[0], mb[1], mb[2], mb[3] };
                *(bf16x4*)&sB[2][sb_n + n][bcol] = (bf16x4){ lb[0], lb[1], lb[2], lb[3] };
            }
        }
        __syncthreads();
        // ---- compute: 8 split-product passes, fixed order (largest first) ----
        const int SA[8] = { 0, 0, 1, 1, 0, 2, 1, 2 };
        const int SB[8] = { 0, 1, 0, 1, 2, 0, 2, 1 };
#pragma unroll
        for (int p = 0; p < 8; p++) {
            int sa = SA[p], sb = SB[p];
            bf16x8 af[4], bfv[4];
#pragma unroll
            for (int i = 0; i < 4; i++)
                af[i] = *(const bf16x8*)&sA[sa][wr + i * 16 + fr][fk];
#pragma unroll
            for (int j = 0; j < 4; j++)
                bfv[j] = *(const bf16x8*)&sB[sb][wc + j * 16 + fr][fk];
#pragma unroll
            for (int i = 0; i < 4; i++)
#pragma unroll
                for (int j = 0; j < 4; j++)
                    acc[i][j] = __builtin_amdgcn_mfma_f32_16x16x32_bf16(
                        af[i], bfv[j], acc[i][j], 0, 0, 0);
        }
    }

    // ---- epilogue: C/D layout col = l&15, row = (l>>4)*4 + reg (m89) ----
    int orow = (l >> 4) << 2;
#pragma unroll
    for (int j = 0; j < 4; j++) {
        int colg = bn + wc + j * 16 + fr;
        float bj = bias[colg];
#pragma unroll
        for (int i = 0; i < 4; i++) {
            int rowg = bm + wr + i * 16 + orow;
#pragma unroll
            for (int r = 0; r < 4; r++) {
                float val = acc[i][j][r] + bj;
                val = (mode == 0) ? fmaxf(val, 0.f) : val / 0.1f;
                Co[(size_t)(rowg + r) * N + colg] = val;
            }
        }
    }
}

// ======== DPP reduce networks to lane 63 (pure VALU) ========
#define DPP6_MAXF(x)                                                              \
    { int _t;                                                                     \
      _t = __builtin_amdgcn_update_dpp(__float_as_int(x), __float_as_int(x),      \
               0x111, 0xf, 0xf, false); x = fmaxf(x, __int_as_float(_t));         \
      _t = __builtin_amdgcn_update_dpp(__float_as_int(x), __float_as_int(x),      \
               0x112, 0xf, 0xf, false); x = fmaxf(x, __int_as_float(_t));         \
      _t = __builtin_amdgcn_update_dpp(__float_as_int(x), __float_as_int(x),      \
               0x114, 0xf, 0xf, false); x = fmaxf(x, __int_as_float(_t));         \
      _t = __builtin_amdgcn_update_dpp(__float_as_int(x), __float_as_int(x),      \
               0x118, 0xf, 0xf, false); x = fmaxf(x, __int_as_float(_t));         \
      _t = __builtin_amdgcn_update_dpp(__float_as_int(x), __float_as_int(x),      \
               0x142, 0xa, 0xf, false); x = fmaxf(x, __int_as_float(_t));         \
      _t = __builtin_amdgcn_update_dpp(__float_as_int(x), __float_as_int(x),      \
               0x143, 0xc, 0xf, false); x = fmaxf(x, __int_as_float(_t)); }

#define DPP6_ADDF(x)                                                              \
    { int _t;                                                                     \
      _t = __builtin_amdgcn_update_dpp(__float_as_int(x), __float_as_int(x),      \
               0x111, 0xf, 0xf, false); x = x + __int_as_float(_t);               \
      _t = __builtin_amdgcn_update_dpp(__float_as_int(x), __float_as_int(x),      \
               0x112, 0xf, 0xf, false); x = x + __int_as_float(_t);               \
      _t = __builtin_amdgcn_update_dpp(__float_as_int(x), __float_as_int(x),      \
               0x114, 0xf, 0xf, false); x = x + __int_as_float(_t);               \
      _t = __builtin_amdgcn_update_dpp(__float_as_int(x), __float_as_int(x),      \
               0x118, 0xf, 0xf, false); x = x + __int_as_float(_t);               \
      _t = __builtin_amdgcn_update_dpp(__float_as_int(x), __float_as_int(x),      \
               0x142, 0xa, 0xf, false); x = x + __int_as_float(_t);               \
      _t = __builtin_amdgcn_update_dpp(__float_as_int(x), __float_as_int(x),      \
               0x143, 0xc, 0xf, false); x = x + __int_as_float(_t); }

// ---------------- Fused Sinkhorn half-iterations (round-9 design).
__global__ __launch_bounds__(256) void sinkhorn_iter(
    const float* __restrict__ A0, float* __restrict__ uu,
    const float* __restrict__ vv, float* __restrict__ ps)
{
    int blk = blockIdx.x;          // NB*8
    int b = blk >> 3, rc = blk & 7;
    int t = threadIdx.x;
    int l = t & 63, w = t >> 6;
    const float* vb = vv + (b << 9);
    float4 v0 = *(const float4*)(vb + 4 * l);
    float4 v1 = *(const float4*)(vb + 256 + 4 * l);
    int row0 = (rc << 6) + (w << 4);
    const float* base = A0 + ((size_t)((b << 9) + row0) << 9);

    float cs0 = 0.f, cs1 = 0.f, cs2 = 0.f, cs3 = 0.f;
    float cs4 = 0.f, cs5 = 0.f, cs6 = 0.f, cs7 = 0.f;

    for (int rr = 0; rr < 16; ++rr) {
        const float* rowp = base + ((size_t)rr << 9);
        float4 a0 = *(const float4*)(rowp + 4 * l);
        float4 a1 = *(const float4*)(rowp + 256 + 4 * l);
        float x0 = a0.x + v0.x, x1 = a0.y + v0.y;
        float x2 = a0.z + v0.z, x3 = a0.w + v0.w;
        float x4 = a1.x + v1.x, x5 = a1.y + v1.y;
        float x6 = a1.z + v1.z, x7 = a1.w + v1.w;
        float m = fmaxf(fmaxf(fmaxf(x0, x1), fmaxf(x2, x3)),
                        fmaxf(fmaxf(x4, x5), fmaxf(x6, x7)));
        DPP6_MAXF(m)
        int mi = __builtin_amdgcn_readlane(__float_as_int(m), 63);
        m = __int_as_float(mi);
        float e0 = __expf(x0 - m), e1 = __expf(x1 - m);
        float e2 = __expf(x2 - m), e3 = __expf(x3 - m);
        float e4 = __expf(x4 - m), e5 = __expf(x5 - m);
        float e6 = __expf(x6 - m), e7 = __expf(x7 - m);
        float s = ((e0 + e1) + (e2 + e3)) + ((e4 + e5) + (e6 + e7));
        DPP6_ADDF(s)
        int si = __builtin_amdgcn_readlane(__float_as_int(s), 63);
        s = __int_as_float(si);
        float inv = 1.0f / s;
        cs0 += e0 * inv; cs1 += e1 * inv; cs2 += e2 * inv; cs3 += e3 * inv;
        cs4 += e4 * inv; cs5 += e5 * inv; cs6 += e6 * inv; cs7 += e7 * inv;
        if (l == 63) uu[(b << 9) + row0 + rr] = -(m + __logf(s));
    }

    __shared__ float sacc[4][512];
    float4 w0; w0.x = cs0; w0.y = cs1; w0.z = cs2; w0.w = cs3;
    float4 w1; w1.x = cs4; w1.y = cs5; w1.z = cs6; w1.w = cs7;
    *(float4*)&sacc[w][4 * l] = w0;
    *(float4*)&sacc[w][256 + 4 * l] = w1;
    __syncthreads();
    float pA = sacc[0][t] + sacc[1][t] + sacc[2][t] + sacc[3][t];
    float pB = sacc[0][256 + t] + sacc[1][256 + t] + sacc[2][256 + t] + sacc[3][256 + t];
    int o = ((b << 3) + rc) * NG;
    ps[o + t] = pA;
    ps[o + 256 + t] = pB;
}

// ---------------- combine 8 linear partials -> v' = v - log(colsum)
__global__ __launch_bounds__(256) void col_combine_lin(
    const float* __restrict__ ps, float* __restrict__ vv)
{
    int tid = blockIdx.x * 256 + threadIdx.x;  // NB*NG
    int b = tid >> 9, j = tid & 511;
    float S = 0.f;
#pragma unroll
    for (int rc = 0; rc < 8; rc++) S += ps[((b << 3) + rc) * NG + j];
    vv[tid] = vv[tid] - __logf(S);
}

// wave-cooperative masked row argmax over cols 8l..8l+7 per lane.
__device__ __forceinline__ void masked_row_argmax(
    const float* __restrict__ rowp, int l, unsigned int free8, int rr,
    float& outV, int& outF)
{
    float4 x0 = *(const float4*)(rowp + 8 * l);
    float4 x1 = *(const float4*)(rowp + 8 * l + 4);
    float q0 = (free8 & 1u)   ? x0.x : -1.0f;
    float q1 = (free8 & 2u)   ? x0.y : -1.0f;
    float q2 = (free8 & 4u)   ? x0.z : -1.0f;
    float q3 = (free8 & 8u)   ? x0.w : -1.0f;
    float q4 = (free8 & 16u)  ? x1.x : -1.0f;
    float q5 = (free8 & 32u)  ? x1.y : -1.0f;
    float q6 = (free8 & 64u)  ? x1.z : -1.0f;
    float q7 = (free8 & 128u) ? x1.w : -1.0f;
    float lm = fmaxf(fmaxf(fmaxf(q0, q1), fmaxf(q2, q3)),
                     fmaxf(fmaxf(q4, q5), fmaxf(q6, q7)));
    int sb = (rr << 9) + 8 * l;
    int lf = 0x7FFFFFFF;
    lf = (q7 == lm) ? sb + 7 : lf;
    lf = (q6 == lm) ? sb + 6 : lf;
    lf = (q5 == lm) ? sb + 5 : lf;
    lf = (q4 == lm) ? sb + 4 : lf;
    lf = (q3 == lm) ? sb + 3 : lf;
    lf = (q2 == lm) ? sb + 2 : lf;
    lf = (q1 == lm) ? sb + 1 : lf;
    lf = (q0 == lm) ? sb + 0 : lf;
    float gg = lm;
    DPP6_MAXF(gg)
    int ggi = __builtin_amdgcn_readlane(__float_as_int(gg), 63);
    float g1 = __int_as_float(ggi);
    unsigned long long tb = __ballot(lm == g1);
    int tl = __ffsll(tb) - 1;
    outV = g1;
    outF = __builtin_amdgcn_readlane(lf, tl);
}

// ---------------- P = exp((A0+u)+v) (libm expf) + per-row argmax + state init.
__global__ __launch_bounds__(256) void p_rowmax(
    const float* __restrict__ A0, const float* __restrict__ uu,
    const float* __restrict__ vv, float* __restrict__ P,
    int* __restrict__ rbCr, int* __restrict__ rbCc,
    unsigned long long* __restrict__ freeRow,
    unsigned long long* __restrict__ freeCol,
    int* __restrict__ remaining)
{
    if (blockIdx.x == 0) {
        int t = threadIdx.x;
        freeRow[t] = ~0ULL;
        freeCol[t] = ~0ULL;
        if (t < NB) remaining[t] = NG;
    }
    int wrow = blockIdx.x * 4 + (threadIdx.x >> 6);
    int l = threadIdx.x & 63;
    int b = wrow >> 9;
    float ur = uu[wrow];
    const float* vb = vv + (b << 9);
    size_t ro = (size_t)wrow << 9;
    float4 a0 = *(const float4*)(A0 + ro + 8 * l);
    float4 a1 = *(const float4*)(A0 + ro + 8 * l + 4);
    float4 v0 = *(const float4*)(vb + 8 * l);
    float4 v1 = *(const float4*)(vb + 8 * l + 4);
    float p0 = expf(a0.x + ur + v0.x);
    float p1 = expf(a0.y + ur + v0.y);
    float p2 = expf(a0.z + ur + v0.z);
    float p3 = expf(a0.w + ur + v0.w);
    float p4 = expf(a1.x + ur + v1.x);
    float p5 = expf(a1.y + ur + v1.y);
    float p6 = expf(a1.z + ur + v1.z);
    float p7 = expf(a1.w + ur + v1.w);
    float4 o0; o0.x = p0; o0.y = p1; o0.z = p2; o0.w = p3;
    float4 o1; o1.x = p4; o1.y = p5; o1.z = p6; o1.w = p7;
    *(float4*)(P + ro + 8 * l) = o0;
    *(float4*)(P + ro + 8 * l + 4) = o1;
    float mv = fmaxf(fmaxf(fmaxf(p0, p1), fmaxf(p2, p3)),
                     fmaxf(fmaxf(p4, p5), fmaxf(p6, p7)));
    int cb = 8 * l;
    int f = 0x7FFFFFFF;
    f = (p7 == mv) ? cb + 7 : f;
    f = (p6 == mv) ? cb + 6 : f;
    f = (p5 == mv) ? cb + 5 : f;
    f = (p4 == mv) ? cb + 4 : f;
    f = (p3 == mv) ? cb + 3 : f;
    f = (p2 == mv) ? cb + 2 : f;
    f = (p1 == mv) ? cb + 1 : f;
    f = (p0 == mv) ? cb + 0 : f;
    float g = mv;
    DPP6_MAXF(g)
    int gi = __builtin_amdgcn_readlane(__float_as_int(g), 63);
    float gm = __int_as_float(gi);
    unsigned long long tb = __ballot(mv == gm);
    int tl = __ffsll(tb) - 1;
    int bestc = __builtin_amdgcn_readlane(f, tl);
    if (l == 0) { rbCr[wrow] = bestc; rbCc[wrow] = -1; }
}

// ---------------- One parallel mutual-max round (exact greedy equivalence).
__global__ __launch_bounds__(512) void mutual_round(
    const float* __restrict__ P, int* __restrict__ rbCr, int* __restrict__ rbCc,
    unsigned long long* __restrict__ freeRow,
    unsigned long long* __restrict__ freeCol,
    int* __restrict__ remaining, int* __restrict__ permInt)
{
    int b = blockIdx.x;
    if (remaining[b] == 0) return;
    int t = threadIdx.x;
    int l = t & 63;
    int w = t >> 6;
    const float* Pb = P + (size_t)b * NG * NG;

    __shared__ unsigned int fr[16], fc[16];
    __shared__ int sRC[NG];
    __shared__ int sCC[NG];
    __shared__ int freeList[NG];
    __shared__ int dirtyRows[NG];
    __shared__ int nFree, nDirtyRow, takeCnt;
    __shared__ int wCnt[8], wOff[8];

    if (t < 8) {
        unsigned long long x = freeRow[b * 8 + t];
        fr[2 * t] = (unsigned)x; fr[2 * t + 1] = (unsigned)(x >> 32);
    } else if (t < 16) {
        int i = t - 8;
        unsigned long long x = freeCol[b * 8 + i];
        fc[2 * i] = (unsigned)x; fc[2 * i + 1] = (unsigned)(x >> 32);
    }
    sRC[t] = rbCr[(b << 9) + t];
    sCC[t] = rbCc[(b << 9) + t];
    if (t == 0) { nDirtyRow = 0; takeCnt = 0; }
    __syncthreads();

    bool isFree = (fr[t >> 5] >> (t & 31)) & 1u;
    unsigned long long bm = __ballot(isFree);
    if (l == 0) wCnt[w] = __popcll(bm);
    if (isFree) {
        int c = sRC[t];
        if (!((fc[c >> 5] >> (c & 31)) & 1u)) {
            int d = atomicAdd(&nDirtyRow, 1);
            dirtyRows[d] = t;
        }
    }
    __syncthreads();
    if (t == 0) {
        int s = 0;
#pragma unroll
        for (int i = 0; i < 8; i++) { wOff[i] = s; s += wCnt[i]; }
        nFree = s;
    }
    __syncthreads();
    if (isFree) {
        int rank = __popcll(bm & ((1ULL << l) - 1ULL));
        freeList[wOff[w] + rank] = t;
    }
    __syncthreads();

    int nd = nDirtyRow;
    for (int d = w; d < nd; d += 8) {
        int r = dirtyRows[d];
        unsigned int free8 = (fc[l >> 2] >> ((l & 3) * 8)) & 0xFFu;
        float nv; int nf;
        masked_row_argmax(Pb + ((size_t)r << 9), l, free8, r, nv, nf);
        if (l == 0) {
            int c = nf & 511;
            sRC[r] = c;
            rbCr[(b << 9) + r] = c;
        }
    }
    __syncthreads();

    bool colFree = (fc[t >> 5] >> (t & 31)) & 1u;
    int cachedR = sCC[t];
    bool colDirty = colFree &&
        (cachedR < 0 || !((fr[cachedR >> 5] >> (cachedR & 31)) & 1u));
    if (colDirty) {
        float best = -1.f; int bestr = 0x7FFFFFFF;
        int nf2 = nFree;
        int i = 0;
        for (; i + 4 <= nf2; i += 4) {
            int r0 = freeList[i], r1 = freeList[i + 1];
            int r2 = freeList[i + 2], r3 = freeList[i + 3];
            float v0 = Pb[((size_t)r0 << 9) + t];
            float v1 = Pb[((size_t)r1 << 9) + t];
            float v2 = Pb[((size_t)r2 << 9) + t];
            float v3 = Pb[((size_t)r3 << 9) + t];
            if (v0 > best) { best = v0; bestr = r0; }
            if (v1 > best) { best = v1; bestr = r1; }
            if (v2 > best) { best = v2; bestr = r2; }
            if (v3 > best) { best = v3; bestr = r3; }
        }
        for (; i < nf2; ++i) {
            int ri = freeList[i];
            float vv2 = Pb[((size_t)ri << 9) + t];
            if (vv2 > best) { best = vv2; bestr = ri; }
        }
        sCC[t] = bestr;
        rbCc[(b << 9) + t] = bestr;
    }
    __syncthreads();

    if (colFree) {
        int r = sCC[t];
        if (r >= 0 && r < NG && sRC[r] == t) {
            permInt[(b << 9) + r] = t;
            atomicAnd(&fr[r >> 5], ~(1u << (r & 31)));
            atomicAnd(&fc[t >> 5], ~(1u << (t & 31)));
            atomicAdd(&takeCnt, 1);
        }
    }
    __syncthreads();
    if (t < 8) {
        freeRow[b * 8 + t] =
            ((unsigned long long)fr[2 * t + 1] << 32) | fr[2 * t];
    } else if (t < 16) {
        int i = t - 8;
        freeCol[b * 8 + i] =
            ((unsigned long long)fc[2 * i + 1] << 32) | fc[2 * i];
    }
    if (t == 0) remaining[b] = remaining[b] - takeCnt;
}

// ---------------- Exact sequential cleanup (rarely does work).
__global__ __launch_bounds__(64) void greedy_cleanup(
    const float* __restrict__ P,
    const unsigned long long* __restrict__ freeRow,
    const unsigned long long* __restrict__ freeCol,
    const int* __restrict__ remaining, int* __restrict__ permInt)
{
    int b = blockIdx.x;
    if (remaining[b] == 0) return;
    int l = threadIdx.x;
    const float* Pb = P + (size_t)b * NG * NG;

    unsigned long long wR = freeRow[b * 8 + (l >> 3)];
    unsigned int myRows = (unsigned int)((wR >> ((l & 7) * 8)) & 0xFF);
    unsigned long long wC = freeCol[b * 8 + (l >> 3)];
    unsigned int free8 = (unsigned int)((wC >> ((l & 7) * 8)) & 0xFF);

    float rv[8]; int rf[8];
#pragma unroll
    for (int k = 0; k < 8; k++) { rv[k] = -1.f; rf[k] = 0x7FFFFFFF; }

    int dmk = (int)myRows;
    unsigned long long act = __ballot(dmk != 0);
    while (act) {
        int src = __ffsll(act) - 1;
        int kk = __ffs(__builtin_amdgcn_readlane(dmk, src)) - 1;
        if (l == src) dmk &= ~(1 << kk);
        int rr = (src << 3) + kk;
        float nv; int nf;
        masked_row_argmax(Pb + ((size_t)rr << 9), l, free8, rr, nv, nf);
        bool upd = (l == src);
        rv[0] = (upd && kk == 0) ? nv : rv[0]; rf[0] = (upd && kk == 0) ? nf : rf[0];
        rv[1] = (upd && kk == 1) ? nv : rv[1]; rf[1] = (upd && kk == 1) ? nf : rf[1];
        rv[2] = (upd && kk == 2) ? nv : rv[2]; rf[2] = (upd && kk == 2) ? nf : rf[2];
        rv[3] = (upd && kk == 3) ? nv : rv[3]; rf[3] = (upd && kk == 3) ? nf : rf[3];
        rv[4] = (upd && kk == 4) ? nv : rv[4]; rf[4] = (upd && kk == 4) ? nf : rf[4];
        rv[5] = (upd && kk == 5) ? nv : rv[5]; rf[5] = (upd && kk == 5) ? nf : rf[5];
        rv[6] = (upd && kk == 6) ? nv : rv[6]; rf[6] = (upd && kk == 6) ? nf : rf[6];
        rv[7] = (upd && kk == 7) ? nv : rv[7]; rf[7] = (upd && kk == 7) ? nf : rf[7];
        act = __ballot(dmk != 0);
    }

    for (int step = 0; step < NG; ++step) {
        float mv = fmaxf(fmaxf(fmaxf(rv[0], rv[1]), fmaxf(rv[2], rv[3])),
                         fmaxf(fmaxf(rv[4], rv[5]), fmaxf(rv[6], rv[7])));
        int f = 0x7FFFFFFF;
        f = (rv[7] == mv) ? rf[7] : f;
        f = (rv[6] == mv) ? rf[6] : f;
        f = (rv[5] == mv) ? rf[5] : f;
        f = (rv[4] == mv) ? rf[4] : f;
        f = (rv[3] == mv) ? rf[3] : f;
        f = (rv[2] == mv) ? rf[2] : f;
        f = (rv[1] == mv) ? rf[1] : f;
        f = (rv[0] == mv) ? rf[0] : f;
        float g = mv;
        DPP6_MAXF(g)
        int gi = __builtin_amdgcn_readlane(__float_as_int(g), 63);
        float gm = __int_as_float(gi);
        if (gm < 0.f) break;
        unsigned long long tb = __ballot(mv == gm);
        int tl = __ffsll(tb) - 1;
        int bestf = __builtin_amdgcn_readlane(f, tl);
        int r = bestf >> 9, c = bestf & 511;
        if (l == 0) permInt[(b << 9) + r] = c;
        if (l == (c >> 3)) free8 &= ~(1u << (c & 7));
        int rl = r - (l << 3);
        int dm2 = 0;
#pragma unroll
        for (int k = 0; k < 8; k++) {
            bool alive = rv[k] >= 0.f;
            bool cm = ((rf[k] ^ c) & 511) == 0;
            bool taken = (rl == k);
            if (taken) rv[k] = -1.f;
            dm2 |= (alive && cm && !taken) ? (1 << k) : 0;
        }
        unsigned long long act2 = __ballot(dm2 != 0);
        while (act2) {
            int src = __ffsll(act2) - 1;
            int kk = __ffs(__builtin_amdgcn_readlane(dm2, src)) - 1;
            if (l == src) dm2 &= ~(1 << kk);
            int rr = (src << 3) + kk;
            float nv; int nf;
            masked_row_argmax(Pb + ((size_t)rr << 9), l, free8, rr, nv, nf);
            bool upd = (l == src);
            rv[0] = (upd && kk == 0) ? nv : rv[0]; rf[0] = (upd && kk == 0) ? nf : rf[0];
            rv[1] = (upd && kk == 1) ? nv : rv[1]; rf[1] = (upd && kk == 1) ? nf : rf[1];
            rv[2] = (upd && kk == 2) ? nv : rv[2]; rf[2] = (upd && kk == 2) ? nf : rf[2];
            rv[3] = (upd && kk == 3) ? nv : rv[3]; rf[3] = (upd && kk == 3) ? nf : rf[3];
            rv[4] = (upd && kk == 4) ? nv : rv[4]; rf[4] = (upd && kk == 4) ? nf : rf[4];
            rv[5] = (upd && kk == 5) ? nv : rv[5]; rf[5] = (upd && kk == 5) ? nf : rf[5];
            rv[6] = (upd && kk == 6) ? nv : rv[6]; rf[6] = (upd && kk == 6) ? nf : rf[6];
            rv[7] = (upd && kk == 7) ? nv : rv[7]; rf[7] = (upd && kk == 7) ? nf : rf[7];
            act2 = __ballot(dm2 != 0);
        }
    }
}

// ---------------- apply permutation (coords + feats + perm float, fused)
__global__ void scatter_all(const float* __restrict__ coords,
    const float* __restrict__ feats, const int* __restrict__ perm,
    float* __restrict__ dstCoords, float* __restrict__ dstFeats,
    float* __restrict__ permF)
{
    int tid = blockIdx.x * 256 + threadIdx.x;   // NB*NG*96 float4s
    int rc = tid / 96;
    int q = tid - rc * 96;
    int b = rc >> 9;
    int p = perm[rc];
    const float4* s4 = (const float4*)(feats + (size_t)rc * NC);
    float4* d4 = (float4*)(dstFeats + ((size_t)(b << 9) + p) * NC);
    d4[q] = s4[q];
    if (q == 0) {
        permF[rc] = (float)p;
        size_t so = (size_t)rc * 3;
        size_t dd = ((size_t)(b << 9) + p) * 3;
        dstCoords[dd] = coords[so];
        dstCoords[dd + 1] = coords[so + 1];
        dstCoords[dd + 2] = coords[so + 2];
    }
}

extern "C" void kernel_launch(void* const* d_in, const int* in_sizes, int n_in,
                              void* d_out, int out_size, void* d_ws, size_t ws_size,
                              hipStream_t stream)
{
    const float* coords = (const float*)d_in[0];
    const float* feats  = (const float*)d_in[1];
    const float* W1 = (const float*)d_in[2];
    const float* b1 = (const float*)d_in[3];
    const float* W2 = (const float*)d_in[4];
    const float* b2 = (const float*)d_in[5];

    float* out = (float*)d_out;
    float* outCoords = out;
    float* outFeats  = out + (size_t)NB * NG * 3;
    float* outPerm   = out + (size_t)NB * NG * 3 + (size_t)NB * NG * NC;

    float* ws = (float*)d_ws;
    float* h   = ws;                                  // 16384*768 (reused as P)
    float* A0  = h + (size_t)NB * NG * NH;            // 16384*512
    float* u   = A0 + (size_t)NB * NG * NG;           // 16384
    float* v   = u + NB * NG;                         // 16384
    float* pm  = v + NB * NG;                         // 32*8*512 (unused)
    float* ps  = pm + NB * 8 * NG;                    // 32*8*512
    int* rbCr  = (int*)(ps + NB * 8 * NG);            // 16384
    int* rbCc  = rbCr + NB * NG;                      // 16384
    unsigned long long* freeRow = (unsigned long long*)(rbCc + NB * NG); // 256
    unsigned long long* freeCol = freeRow + NB * 8;   // 256
    int* remaining = (int*)(freeCol + NB * 8);        // 32
    int* permInt   = remaining + 32;                  // 16384

    const int M = NB * NG;  // 16384

    // h = relu(feats @ W1 + b1)   [bf16x3 split MFMA]
    gemm_bias_mfma<<<dim3((M / 128) * (NH / 128)), 256, 0, stream>>>(
        feats, W1, b1, h, M, NH, NC, 0);
    // A0 = (h @ W2 + b2) / TAU    [bf16x3 split MFMA]
    gemm_bias_mfma<<<dim3((M / 128) * (NG / 128)), 256, 0, stream>>>(
        h, W2, b2, A0, M, NG, NH, 1);

    hipMemsetAsync(v, 0, (size_t)NB * NG * sizeof(float), stream);

    for (int it = 0; it < 10; ++it) {
        sinkhorn_iter<<<dim3(NB * 8), 256, 0, stream>>>(A0, u, v, ps);
        col_combine_lin<<<dim3(M / 256), 256, 0, stream>>>(ps, v);
    }

    float* P = h;
    p_rowmax<<<dim3(M / 4), 256, 0, stream>>>(A0, u, v, P, rbCr, rbCc,
                                              freeRow, freeCol, remaining);

    for (int r = 0; r < 6; ++r)
        mutual_round<<<dim3(NB), 512, 0, stream>>>(P, rbCr, rbCc, freeRow,
                                                   freeCol, remaining, permInt);

    greedy_cleanup<<<dim3(NB), 64, 0, stream>>>(P, freeRow, freeCol,
                                                remaining, permInt);

    scatter_all<<<dim3((NB * NG * 96) / 256), 256, 0, stream>>>(
        coords, feats, permInt, outCoords, outFeats, outPerm);
}

// Round 14
// 400.153 us; speedup vs baseline: 1.3791x; 1.0555x over previous
//
#include <hip/hip_runtime.h>
#include <math.h>

#define NB 32
#define NG 512
#define NC 384
#define NH 768

typedef float f32x4v __attribute__((ext_vector_type(4)));
typedef __bf16 bf16_t;
typedef bf16_t bf16x8 __attribute__((ext_vector_type(8)));
typedef bf16_t bf16x4 __attribute__((ext_vector_type(4)));

#define LDSK 40   // 32 k (permuted) + 8 pad; row stride 80 B (16B-aligned)

__device__ __forceinline__ void split3(float x, bf16_t& h, bf16_t& m, bf16_t& lo)
{
    h = (bf16_t)x;
    float r1 = x - (float)h;
    m = (bf16_t)r1;
    float r2 = r1 - (float)m;
    lo = (bf16_t)r2;
}

// ---------------- GEMM via bf16 MFMA, exact 3-way split, 6 products
// (hh,hm,mh,mm,hl,lh; dropped ml+lm+ll ~ 2^-24..2^-32 => fp32-reorder-noise
// class). Register-blocked: all 24 fragments loaded ONCE per K-chunk (LDS
// reads 64 -> 24 per chunk vs round-13), then 96 MFMAs from registers.
// 128x128 tile, 4 waves (2x2 of 64x64), K-chunk 32. LDS k-dim PERMUTED so
// each fragment (k = (l>>4)*4 + (j&3) + 16*(j>>2)) is one ds_read_b128:
// pos(k) = ((k>>2)&3)*8 + (k>>4)*4 + (k&3).
// mode 0: relu, mode 1: /0.1 (scores/TAU). Deterministic fixed order.
__global__ __launch_bounds__(256, 2) void gemm_bias_mfma(
    const float* __restrict__ A, const float* __restrict__ Bw,
    const float* __restrict__ bias, float* __restrict__ Co,
    int M, int N, int K, int mode)
{
    __shared__ __align__(16) bf16_t sA[3][128][LDSK];
    __shared__ __align__(16) bf16_t sB[3][128][LDSK];   // B^T: [col][k-pos]
    int ntiles = N >> 7;
    int bm = (blockIdx.x / ntiles) << 7;
    int bn = (blockIdx.x % ntiles) << 7;
    int t = threadIdx.x;
    int l = t & 63;
    int w = t >> 6;
    int wr = (w >> 1) << 6;       // wave row base (0/64)
    int wc = (w & 1) << 6;        // wave col base (0/64)
    int fr = l & 15;              // frag row/col
    int fk = (l >> 4) << 3;       // frag k-pos base (0,8,16,24)

    // staging: A: thread -> (row = t>>1, khalf = (t&1)*16)
    int sa_row = t >> 1;
    int sa_kh = (t & 1) << 4;
    int hsel = (sa_kh >> 4) << 2;      // 0 or 4
    // staging: B: thread -> (k quad = (t&7)*4, col quad = (t>>3)*4)
    int sb_k = (t & 7) << 2;
    int sb_n = (t >> 3) << 2;
    int bcol = ((sb_k >> 2) & 3) * 8 + ((sb_k >> 4) << 2);

    f32x4v acc[4][4];
#pragma unroll
    for (int i = 0; i < 4; i++)
#pragma unroll
        for (int j = 0; j < 4; j++) acc[i][j] = (f32x4v)(0.f);

    for (int kc = 0; kc < K; kc += 32) {
        __syncthreads();
        // ---- stage A (128x32 fp32 -> 3 bf16 splits, k-permuted) ----
        {
            const float* ap = A + (size_t)(bm + sa_row) * K + kc + sa_kh;
            float4 q0 = *(const float4*)(ap + 0);
            float4 q1 = *(const float4*)(ap + 4);
            float4 q2 = *(const float4*)(ap + 8);
            float4 q3 = *(const float4*)(ap + 12);
            float xs[16] = { q0.x, q0.y, q0.z, q0.w, q1.x, q1.y, q1.z, q1.w,
                             q2.x, q2.y, q2.z, q2.w, q3.x, q3.y, q3.z, q3.w };
            bf16_t hs[16], ms[16], ls[16];
#pragma unroll
            for (int e = 0; e < 16; e++) split3(xs[e], hs[e], ms[e], ls[e]);
#pragma unroll
            for (int qd = 0; qd < 4; qd++) {
                int col = qd * 8 + hsel;
                *(bf16x4*)&sA[0][sa_row][col] =
                    (bf16x4){ hs[4 * qd], hs[4 * qd + 1], hs[4 * qd + 2], hs[4 * qd + 3] };
                *(bf16x4*)&sA[1][sa_row][col] =
                    (bf16x4){ ms[4 * qd], ms[4 * qd + 1], ms[4 * qd + 2], ms[4 * qd + 3] };
                *(bf16x4*)&sA[2][sa_row][col] =
                    (bf16x4){ ls[4 * qd], ls[4 * qd + 1], ls[4 * qd + 2], ls[4 * qd + 3] };
            }
        }
        // ---- stage B (32x128 fp32 -> B^T 3 bf16 splits, k-permuted) ----
        {
            float bbv[4][4];
#pragma unroll
            for (int kk = 0; kk < 4; kk++) {
                float4 bq = *(const float4*)(Bw + (size_t)(kc + sb_k + kk) * N + bn + sb_n);
                bbv[kk][0] = bq.x; bbv[kk][1] = bq.y; bbv[kk][2] = bq.z; bbv[kk][3] = bq.w;
            }
#pragma unroll
            for (int n = 0; n < 4; n++) {
                bf16_t hb[4], mb[4], lb[4];
#pragma unroll
                for (int kk = 0; kk < 4; kk++) split3(bbv[kk][n], hb[kk], mb[kk], lb[kk]);
                *(bf16x4*)&sB[0][sb_n + n][bcol] = (bf16x4){ hb[0], hb[1], hb[2], hb[3] };
                *(bf16x4*)&sB[1][sb_n + n][bcol] = (bf16x4){ mb[0], mb[1], mb[2], mb[3] };
                *(bf16x4*)&sB[2][sb_n + n][bcol] = (bf16x4){ lb[0], lb[1], lb[2], lb[3] };
            }
        }
        __syncthreads();
        // ---- load all fragments once (24 x ds_read_b128), then 96 MFMAs ----
        bf16x8 afH[4], afM[4], afL[4], bfH[4], bfM[4], bfL[4];
#pragma unroll
        for (int i = 0; i < 4; i++) {
            afH[i] = *(const bf16x8*)&sA[0][wr + i * 16 + fr][fk];
            afM[i] = *(const bf16x8*)&sA[1][wr + i * 16 + fr][fk];
            afL[i] = *(const bf16x8*)&sA[2][wr + i * 16 + fr][fk];
            bfH[i] = *(const bf16x8*)&sB[0][wc + i * 16 + fr][fk];
            bfM[i] = *(const bf16x8*)&sB[1][wc + i * 16 + fr][fk];
            bfL[i] = *(const bf16x8*)&sB[2][wc + i * 16 + fr][fk];
        }
        // per-accumulator product order preserved vs round 13:
        // hh, hm, mh, mm, hl, lh (ml/lm dropped)
#pragma unroll
        for (int i = 0; i < 4; i++)
#pragma unroll
            for (int j = 0; j < 4; j++) {
                acc[i][j] = __builtin_amdgcn_mfma_f32_16x16x32_bf16(
                    afH[i], bfH[j], acc[i][j], 0, 0, 0);
                acc[i][j] = __builtin_amdgcn_mfma_f32_16x16x32_bf16(
                    afH[i], bfM[j], acc[i][j], 0, 0, 0);
                acc[i][j] = __builtin_amdgcn_mfma_f32_16x16x32_bf16(
                    afM[i], bfH[j], acc[i][j], 0, 0, 0);
                acc[i][j] = __builtin_amdgcn_mfma_f32_16x16x32_bf16(
                    afM[i], bfM[j], acc[i][j], 0, 0, 0);
                acc[i][j] = __builtin_amdgcn_mfma_f32_16x16x32_bf16(
                    afH[i], bfL[j], acc[i][j], 0, 0, 0);
                acc[i][j] = __builtin_amdgcn_mfma_f32_16x16x32_bf16(
                    afL[i], bfH[j], acc[i][j], 0, 0, 0);
            }
    }

    // ---- epilogue: C/D layout col = l&15, row = (l>>4)*4 + reg (m89) ----
    int orow = (l >> 4) << 2;
#pragma unroll
    for (int j = 0; j < 4; j++) {
        int colg = bn + wc + j * 16 + fr;
        float bj = bias[colg];
#pragma unroll
        for (int i = 0; i < 4; i++) {
            int rowg = bm + wr + i * 16 + orow;
#pragma unroll
            for (int r = 0; r < 4; r++) {
                float val = acc[i][j][r] + bj;
                val = (mode == 0) ? fmaxf(val, 0.f) : val / 0.1f;
                Co[(size_t)(rowg + r) * N + colg] = val;
            }
        }
    }
}

// ======== DPP reduce networks to lane 63 (pure VALU) ========
#define DPP6_MAXF(x)                                                              \
    { int _t;                                                                     \
      _t = __builtin_amdgcn_update_dpp(__float_as_int(x), __float_as_int(x),      \
               0x111, 0xf, 0xf, false); x = fmaxf(x, __int_as_float(_t));         \
      _t = __builtin_amdgcn_update_dpp(__float_as_int(x), __float_as_int(x),      \
               0x112, 0xf, 0xf, false); x = fmaxf(x, __int_as_float(_t));         \
      _t = __builtin_amdgcn_update_dpp(__float_as_int(x), __float_as_int(x),      \
               0x114, 0xf, 0xf, false); x = fmaxf(x, __int_as_float(_t));         \
      _t = __builtin_amdgcn_update_dpp(__float_as_int(x), __float_as_int(x),      \
               0x118, 0xf, 0xf, false); x = fmaxf(x, __int_as_float(_t));         \
      _t = __builtin_amdgcn_update_dpp(__float_as_int(x), __float_as_int(x),      \
               0x142, 0xa, 0xf, false); x = fmaxf(x, __int_as_float(_t));         \
      _t = __builtin_amdgcn_update_dpp(__float_as_int(x), __float_as_int(x),      \
               0x143, 0xc, 0xf, false); x = fmaxf(x, __int_as_float(_t)); }

#define DPP6_ADDF(x)                                                              \
    { int _t;                                                                     \
      _t = __builtin_amdgcn_update_dpp(__float_as_int(x), __float_as_int(x),      \
               0x111, 0xf, 0xf, false); x = x + __int_as_float(_t);               \
      _t = __builtin_amdgcn_update_dpp(__float_as_int(x), __float_as_int(x),      \
               0x112, 0xf, 0xf, false); x = x + __int_as_float(_t);               \
      _t = __builtin_amdgcn_update_dpp(__float_as_int(x), __float_as_int(x),      \
               0x114, 0xf, 0xf, false); x = x + __int_as_float(_t);               \
      _t = __builtin_amdgcn_update_dpp(__float_as_int(x), __float_as_int(x),      \
               0x118, 0xf, 0xf, false); x = x + __int_as_float(_t);               \
      _t = __builtin_amdgcn_update_dpp(__float_as_int(x), __float_as_int(x),      \
               0x142, 0xa, 0xf, false); x = x + __int_as_float(_t);               \
      _t = __builtin_amdgcn_update_dpp(__float_as_int(x), __float_as_int(x),      \
               0x143, 0xc, 0xf, false); x = x + __int_as_float(_t); }

// ---------------- Fused Sinkhorn half-iterations (round-9 design).
__global__ __launch_bounds__(256) void sinkhorn_iter(
    const float* __restrict__ A0, float* __restrict__ uu,
    const float* __restrict__ vv, float* __restrict__ ps)
{
    int blk = blockIdx.x;          // NB*8
    int b = blk >> 3, rc = blk & 7;
    int t = threadIdx.x;
    int l = t & 63, w = t >> 6;
    const float* vb = vv + (b << 9);
    float4 v0 = *(const float4*)(vb + 4 * l);
    float4 v1 = *(const float4*)(vb + 256 + 4 * l);
    int row0 = (rc << 6) + (w << 4);
    const float* base = A0 + ((size_t)((b << 9) + row0) << 9);

    float cs0 = 0.f, cs1 = 0.f, cs2 = 0.f, cs3 = 0.f;
    float cs4 = 0.f, cs5 = 0.f, cs6 = 0.f, cs7 = 0.f;

    for (int rr = 0; rr < 16; ++rr) {
        const float* rowp = base + ((size_t)rr << 9);
        float4 a0 = *(const float4*)(rowp + 4 * l);
        float4 a1 = *(const float4*)(rowp + 256 + 4 * l);
        float x0 = a0.x + v0.x, x1 = a0.y + v0.y;
        float x2 = a0.z + v0.z, x3 = a0.w + v0.w;
        float x4 = a1.x + v1.x, x5 = a1.y + v1.y;
        float x6 = a1.z + v1.z, x7 = a1.w + v1.w;
        float m = fmaxf(fmaxf(fmaxf(x0, x1), fmaxf(x2, x3)),
                        fmaxf(fmaxf(x4, x5), fmaxf(x6, x7)));
        DPP6_MAXF(m)
        int mi = __builtin_amdgcn_readlane(__float_as_int(m), 63);
        m = __int_as_float(mi);
        float e0 = __expf(x0 - m), e1 = __expf(x1 - m);
        float e2 = __expf(x2 - m), e3 = __expf(x3 - m);
        float e4 = __expf(x4 - m), e5 = __expf(x5 - m);
        float e6 = __expf(x6 - m), e7 = __expf(x7 - m);
        float s = ((e0 + e1) + (e2 + e3)) + ((e4 + e5) + (e6 + e7));
        DPP6_ADDF(s)
        int si = __builtin_amdgcn_readlane(__float_as_int(s), 63);
        s = __int_as_float(si);
        float inv = 1.0f / s;
        cs0 += e0 * inv; cs1 += e1 * inv; cs2 += e2 * inv; cs3 += e3 * inv;
        cs4 += e4 * inv; cs5 += e5 * inv; cs6 += e6 * inv; cs7 += e7 * inv;
        if (l == 63) uu[(b << 9) + row0 + rr] = -(m + __logf(s));
    }

    __shared__ float sacc[4][512];
    float4 w0; w0.x = cs0; w0.y = cs1; w0.z = cs2; w0.w = cs3;
    float4 w1; w1.x = cs4; w1.y = cs5; w1.z = cs6; w1.w = cs7;
    *(float4*)&sacc[w][4 * l] = w0;
    *(float4*)&sacc[w][256 + 4 * l] = w1;
    __syncthreads();
    float pA = sacc[0][t] + sacc[1][t] + sacc[2][t] + sacc[3][t];
    float pB = sacc[0][256 + t] + sacc[1][256 + t] + sacc[2][256 + t] + sacc[3][256 + t];
    int o = ((b << 3) + rc) * NG;
    ps[o + t] = pA;
    ps[o + 256 + t] = pB;
}

// ---------------- combine 8 linear partials -> v' = v - log(colsum)
__global__ __launch_bounds__(256) void col_combine_lin(
    const float* __restrict__ ps, float* __restrict__ vv)
{
    int tid = blockIdx.x * 256 + threadIdx.x;  // NB*NG
    int b = tid >> 9, j = tid & 511;
    float S = 0.f;
#pragma unroll
    for (int rc = 0; rc < 8; rc++) S += ps[((b << 3) + rc) * NG + j];
    vv[tid] = vv[tid] - __logf(S);
}

// wave-cooperative masked row argmax over cols 8l..8l+7 per lane.
__device__ __forceinline__ void masked_row_argmax(
    const float* __restrict__ rowp, int l, unsigned int free8, int rr,
    float& outV, int& outF)
{
    float4 x0 = *(const float4*)(rowp + 8 * l);
    float4 x1 = *(const float4*)(rowp + 8 * l + 4);
    float q0 = (free8 & 1u)   ? x0.x : -1.0f;
    float q1 = (free8 & 2u)   ? x0.y : -1.0f;
    float q2 = (free8 & 4u)   ? x0.z : -1.0f;
    float q3 = (free8 & 8u)   ? x0.w : -1.0f;
    float q4 = (free8 & 16u)  ? x1.x : -1.0f;
    float q5 = (free8 & 32u)  ? x1.y : -1.0f;
    float q6 = (free8 & 64u)  ? x1.z : -1.0f;
    float q7 = (free8 & 128u) ? x1.w : -1.0f;
    float lm = fmaxf(fmaxf(fmaxf(q0, q1), fmaxf(q2, q3)),
                     fmaxf(fmaxf(q4, q5), fmaxf(q6, q7)));
    int sb = (rr << 9) + 8 * l;
    int lf = 0x7FFFFFFF;
    lf = (q7 == lm) ? sb + 7 : lf;
    lf = (q6 == lm) ? sb + 6 : lf;
    lf = (q5 == lm) ? sb + 5 : lf;
    lf = (q4 == lm) ? sb + 4 : lf;
    lf = (q3 == lm) ? sb + 3 : lf;
    lf = (q2 == lm) ? sb + 2 : lf;
    lf = (q1 == lm) ? sb + 1 : lf;
    lf = (q0 == lm) ? sb + 0 : lf;
    float gg = lm;
    DPP6_MAXF(gg)
    int ggi = __builtin_amdgcn_readlane(__float_as_int(gg), 63);
    float g1 = __int_as_float(ggi);
    unsigned long long tb = __ballot(lm == g1);
    int tl = __ffsll(tb) - 1;
    outV = g1;
    outF = __builtin_amdgcn_readlane(lf, tl);
}

// ---------------- P = exp((A0+u)+v) (libm expf) + per-row argmax + state init.
__global__ __launch_bounds__(256) void p_rowmax(
    const float* __restrict__ A0, const float* __restrict__ uu,
    const float* __restrict__ vv, float* __restrict__ P,
    int* __restrict__ rbCr, int* __restrict__ rbCc,
    unsigned long long* __restrict__ freeRow,
    unsigned long long* __restrict__ freeCol,
    int* __restrict__ remaining)
{
    if (blockIdx.x == 0) {
        int t = threadIdx.x;
        freeRow[t] = ~0ULL;
        freeCol[t] = ~0ULL;
        if (t < NB) remaining[t] = NG;
    }
    int wrow = blockIdx.x * 4 + (threadIdx.x >> 6);
    int l = threadIdx.x & 63;
    int b = wrow >> 9;
    float ur = uu[wrow];
    const float* vb = vv + (b << 9);
    size_t ro = (size_t)wrow << 9;
    float4 a0 = *(const float4*)(A0 + ro + 8 * l);
    float4 a1 = *(const float4*)(A0 + ro + 8 * l + 4);
    float4 v0 = *(const float4*)(vb + 8 * l);
    float4 v1 = *(const float4*)(vb + 8 * l + 4);
    float p0 = expf(a0.x + ur + v0.x);
    float p1 = expf(a0.y + ur + v0.y);
    float p2 = expf(a0.z + ur + v0.z);
    float p3 = expf(a0.w + ur + v0.w);
    float p4 = expf(a1.x + ur + v1.x);
    float p5 = expf(a1.y + ur + v1.y);
    float p6 = expf(a1.z + ur + v1.z);
    float p7 = expf(a1.w + ur + v1.w);
    float4 o0; o0.x = p0; o0.y = p1; o0.z = p2; o0.w = p3;
    float4 o1; o1.x = p4; o1.y = p5; o1.z = p6; o1.w = p7;
    *(float4*)(P + ro + 8 * l) = o0;
    *(float4*)(P + ro + 8 * l + 4) = o1;
    float mv = fmaxf(fmaxf(fmaxf(p0, p1), fmaxf(p2, p3)),
                     fmaxf(fmaxf(p4, p5), fmaxf(p6, p7)));
    int cb = 8 * l;
    int f = 0x7FFFFFFF;
    f = (p7 == mv) ? cb + 7 : f;
    f = (p6 == mv) ? cb + 6 : f;
    f = (p5 == mv) ? cb + 5 : f;
    f = (p4 == mv) ? cb + 4 : f;
    f = (p3 == mv) ? cb + 3 : f;
    f = (p2 == mv) ? cb + 2 : f;
    f = (p1 == mv) ? cb + 1 : f;
    f = (p0 == mv) ? cb + 0 : f;
    float g = mv;
    DPP6_MAXF(g)
    int gi = __builtin_amdgcn_readlane(__float_as_int(g), 63);
    float gm = __int_as_float(gi);
    unsigned long long tb = __ballot(mv == gm);
    int tl = __ffsll(tb) - 1;
    int bestc = __builtin_amdgcn_readlane(f, tl);
    if (l == 0) { rbCr[wrow] = bestc; rbCc[wrow] = -1; }
}

// ---------------- One parallel mutual-max round (exact greedy equivalence).
__global__ __launch_bounds__(512) void mutual_round(
    const float* __restrict__ P, int* __restrict__ rbCr, int* __restrict__ rbCc,
    unsigned long long* __restrict__ freeRow,
    unsigned long long* __restrict__ freeCol,
    int* __restrict__ remaining, int* __restrict__ permInt)
{
    int b = blockIdx.x;
    if (remaining[b] == 0) return;
    int t = threadIdx.x;
    int l = t & 63;
    int w = t >> 6;
    const float* Pb = P + (size_t)b * NG * NG;

    __shared__ unsigned int fr[16], fc[16];
    __shared__ int sRC[NG];
    __shared__ int sCC[NG];
    __shared__ int freeList[NG];
    __shared__ int dirtyRows[NG];
    __shared__ int nFree, nDirtyRow, takeCnt;
    __shared__ int wCnt[8], wOff[8];

    if (t < 8) {
        unsigned long long x = freeRow[b * 8 + t];
        fr[2 * t] = (unsigned)x; fr[2 * t + 1] = (unsigned)(x >> 32);
    } else if (t < 16) {
        int i = t - 8;
        unsigned long long x = freeCol[b * 8 + i];
        fc[2 * i] = (unsigned)x; fc[2 * i + 1] = (unsigned)(x >> 32);
    }
    sRC[t] = rbCr[(b << 9) + t];
    sCC[t] = rbCc[(b << 9) + t];
    if (t == 0) { nDirtyRow = 0; takeCnt = 0; }
    __syncthreads();

    bool isFree = (fr[t >> 5] >> (t & 31)) & 1u;
    unsigned long long bm = __ballot(isFree);
    if (l == 0) wCnt[w] = __popcll(bm);
    if (isFree) {
        int c = sRC[t];
        if (!((fc[c >> 5] >> (c & 31)) & 1u)) {
            int d = atomicAdd(&nDirtyRow, 1);
            dirtyRows[d] = t;
        }
    }
    __syncthreads();
    if (t == 0) {
        int s = 0;
#pragma unroll
        for (int i = 0; i < 8; i++) { wOff[i] = s; s += wCnt[i]; }
        nFree = s;
    }
    __syncthreads();
    if (isFree) {
        int rank = __popcll(bm & ((1ULL << l) - 1ULL));
        freeList[wOff[w] + rank] = t;
    }
    __syncthreads();

    int nd = nDirtyRow;
    for (int d = w; d < nd; d += 8) {
        int r = dirtyRows[d];
        unsigned int free8 = (fc[l >> 2] >> ((l & 3) * 8)) & 0xFFu;
        float nv; int nf;
        masked_row_argmax(Pb + ((size_t)r << 9), l, free8, r, nv, nf);
        if (l == 0) {
            int c = nf & 511;
            sRC[r] = c;
            rbCr[(b << 9) + r] = c;
        }
    }
    __syncthreads();

    bool colFree = (fc[t >> 5] >> (t & 31)) & 1u;
    int cachedR = sCC[t];
    bool colDirty = colFree &&
        (cachedR < 0 || !((fr[cachedR >> 5] >> (cachedR & 31)) & 1u));
    if (colDirty) {
        float best = -1.f; int bestr = 0x7FFFFFFF;
        int nf2 = nFree;
        int i = 0;
        for (; i + 4 <= nf2; i += 4) {
            int r0 = freeList[i], r1 = freeList[i + 1];
            int r2 = freeList[i + 2], r3 = freeList[i + 3];
            float v0 = Pb[((size_t)r0 << 9) + t];
            float v1 = Pb[((size_t)r1 << 9) + t];
            float v2 = Pb[((size_t)r2 << 9) + t];
            float v3 = Pb[((size_t)r3 << 9) + t];
            if (v0 > best) { best = v0; bestr = r0; }
            if (v1 > best) { best = v1; bestr = r1; }
            if (v2 > best) { best = v2; bestr = r2; }
            if (v3 > best) { best = v3; bestr = r3; }
        }
        for (; i < nf2; ++i) {
            int ri = freeList[i];
            float vv2 = Pb[((size_t)ri << 9) + t];
            if (vv2 > best) { best = vv2; bestr = ri; }
        }
        sCC[t] = bestr;
        rbCc[(b << 9) + t] = bestr;
    }
    __syncthreads();

    if (colFree) {
        int r = sCC[t];
        if (r >= 0 && r < NG && sRC[r] == t) {
            permInt[(b << 9) + r] = t;
            atomicAnd(&fr[r >> 5], ~(1u << (r & 31)));
            atomicAnd(&fc[t >> 5], ~(1u << (t & 31)));
            atomicAdd(&takeCnt, 1);
        }
    }
    __syncthreads();
    if (t < 8) {
        freeRow[b * 8 + t] =
            ((unsigned long long)fr[2 * t + 1] << 32) | fr[2 * t];
    } else if (t < 16) {
        int i = t - 8;
        freeCol[b * 8 + i] =
            ((unsigned long long)fc[2 * i + 1] << 32) | fc[2 * i];
    }
    if (t == 0) remaining[b] = remaining[b] - takeCnt;
}

// ---------------- Exact sequential cleanup (rarely does work).
__global__ __launch_bounds__(64) void greedy_cleanup(
    const float* __restrict__ P,
    const unsigned long long* __restrict__ freeRow,
    const unsigned long long* __restrict__ freeCol,
    const int* __restrict__ remaining, int* __restrict__ permInt)
{
    int b = blockIdx.x;
    if (remaining[b] == 0) return;
    int l = threadIdx.x;
    const float* Pb = P + (size_t)b * NG * NG;

    unsigned long long wR = freeRow[b * 8 + (l >> 3)];
    unsigned int myRows = (unsigned int)((wR >> ((l & 7) * 8)) & 0xFF);
    unsigned long long wC = freeCol[b * 8 + (l >> 3)];
    unsigned int free8 = (unsigned int)((wC >> ((l & 7) * 8)) & 0xFF);

    float rv[8]; int rf[8];
#pragma unroll
    for (int k = 0; k < 8; k++) { rv[k] = -1.f; rf[k] = 0x7FFFFFFF; }

    int dmk = (int)myRows;
    unsigned long long act = __ballot(dmk != 0);
    while (act) {
        int src = __ffsll(act) - 1;
        int kk = __ffs(__builtin_amdgcn_readlane(dmk, src)) - 1;
        if (l == src) dmk &= ~(1 << kk);
        int rr = (src << 3) + kk;
        float nv; int nf;
        masked_row_argmax(Pb + ((size_t)rr << 9), l, free8, rr, nv, nf);
        bool upd = (l == src);
        rv[0] = (upd && kk == 0) ? nv : rv[0]; rf[0] = (upd && kk == 0) ? nf : rf[0];
        rv[1] = (upd && kk == 1) ? nv : rv[1]; rf[1] = (upd && kk == 1) ? nf : rf[1];
        rv[2] = (upd && kk == 2) ? nv : rv[2]; rf[2] = (upd && kk == 2) ? nf : rf[2];
        rv[3] = (upd && kk == 3) ? nv : rv[3]; rf[3] = (upd && kk == 3) ? nf : rf[3];
        rv[4] = (upd && kk == 4) ? nv : rv[4]; rf[4] = (upd && kk == 4) ? nf : rf[4];
        rv[5] = (upd && kk == 5) ? nv : rv[5]; rf[5] = (upd && kk == 5) ? nf : rf[5];
        rv[6] = (upd && kk == 6) ? nv : rv[6]; rf[6] = (upd && kk == 6) ? nf : rf[6];
        rv[7] = (upd && kk == 7) ? nv : rv[7]; rf[7] = (upd && kk == 7) ? nf : rf[7];
        act = __ballot(dmk != 0);
    }

    for (int step = 0; step < NG; ++step) {
        float mv = fmaxf(fmaxf(fmaxf(rv[0], rv[1]), fmaxf(rv[2], rv[3])),
                         fmaxf(fmaxf(rv[4], rv[5]), fmaxf(rv[6], rv[7])));
        int f = 0x7FFFFFFF;
        f = (rv[7] == mv) ? rf[7] : f;
        f = (rv[6] == mv) ? rf[6] : f;
        f = (rv[5] == mv) ? rf[5] : f;
        f = (rv[4] == mv) ? rf[4] : f;
        f = (rv[3] == mv) ? rf[3] : f;
        f = (rv[2] == mv) ? rf[2] : f;
        f = (rv[1] == mv) ? rf[1] : f;
        f = (rv[0] == mv) ? rf[0] : f;
        float g = mv;
        DPP6_MAXF(g)
        int gi = __builtin_amdgcn_readlane(__float_as_int(g), 63);
        float gm = __int_as_float(gi);
        if (gm < 0.f) break;
        unsigned long long tb = __ballot(mv == gm);
        int tl = __ffsll(tb) - 1;
        int bestf = __builtin_amdgcn_readlane(f, tl);
        int r = bestf >> 9, c = bestf & 511;
        if (l == 0) permInt[(b << 9) + r] = c;
        if (l == (c >> 3)) free8 &= ~(1u << (c & 7));
        int rl = r - (l << 3);
        int dm2 = 0;
#pragma unroll
        for (int k = 0; k < 8; k++) {
            bool alive = rv[k] >= 0.f;
            bool cm = ((rf[k] ^ c) & 511) == 0;
            bool taken = (rl == k);
            if (taken) rv[k] = -1.f;
            dm2 |= (alive && cm && !taken) ? (1 << k) : 0;
        }
        unsigned long long act2 = __ballot(dm2 != 0);
        while (act2) {
            int src = __ffsll(act2) - 1;
            int kk = __ffs(__builtin_amdgcn_readlane(dm2, src)) - 1;
            if (l == src) dm2 &= ~(1 << kk);
            int rr = (src << 3) + kk;
            float nv; int nf;
            masked_row_argmax(Pb + ((size_t)rr << 9), l, free8, rr, nv, nf);
            bool upd = (l == src);
            rv[0] = (upd && kk == 0) ? nv : rv[0]; rf[0] = (upd && kk == 0) ? nf : rf[0];
            rv[1] = (upd && kk == 1) ? nv : rv[1]; rf[1] = (upd && kk == 1) ? nf : rf[1];
            rv[2] = (upd && kk == 2) ? nv : rv[2]; rf[2] = (upd && kk == 2) ? nf : rf[2];
            rv[3] = (upd && kk == 3) ? nv : rv[3]; rf[3] = (upd && kk == 3) ? nf : rf[3];
            rv[4] = (upd && kk == 4) ? nv : rv[4]; rf[4] = (upd && kk == 4) ? nf : rf[4];
            rv[5] = (upd && kk == 5) ? nv : rv[5]; rf[5] = (upd && kk == 5) ? nf : rf[5];
            rv[6] = (upd && kk == 6) ? nv : rv[6]; rf[6] = (upd && kk == 6) ? nf : rf[6];
            rv[7] = (upd && kk == 7) ? nv : rv[7]; rf[7] = (upd && kk == 7) ? nf : rf[7];
            act2 = __ballot(dm2 != 0);
        }
    }
}

// ---------------- apply permutation (coords + feats + perm float, fused)
__global__ void scatter_all(const float* __restrict__ coords,
    const float* __restrict__ feats, const int* __restrict__ perm,
    float* __restrict__ dstCoords, float* __restrict__ dstFeats,
    float* __restrict__ permF)
{
    int tid = blockIdx.x * 256 + threadIdx.x;   // NB*NG*96 float4s
    int rc = tid / 96;
    int q = tid - rc * 96;
    int b = rc >> 9;
    int p = perm[rc];
    const float4* s4 = (const float4*)(feats + (size_t)rc * NC);
    float4* d4 = (float4*)(dstFeats + ((size_t)(b << 9) + p) * NC);
    d4[q] = s4[q];
    if (q == 0) {
        permF[rc] = (float)p;
        size_t so = (size_t)rc * 3;
        size_t dd = ((size_t)(b << 9) + p) * 3;
        dstCoords[dd] = coords[so];
        dstCoords[dd + 1] = coords[so + 1];
        dstCoords[dd + 2] = coords[so + 2];
    }
}

extern "C" void kernel_launch(void* const* d_in, const int* in_sizes, int n_in,
                              void* d_out, int out_size, void* d_ws, size_t ws_size,
                              hipStream_t stream)
{
    const float* coords = (const float*)d_in[0];
    const float* feats  = (const float*)d_in[1];
    const float* W1 = (const float*)d_in[2];
    const float* b1 = (const float*)d_in[3];
    const float* W2 = (const float*)d_in[4];
    const float* b2 = (const float*)d_in[5];

    float* out = (float*)d_out;
    float* outCoords = out;
    float* outFeats  = out + (size_t)NB * NG * 3;
    float* outPerm   = out + (size_t)NB * NG * 3 + (size_t)NB * NG * NC;

    float* ws = (float*)d_ws;
    float* h   = ws;                                  // 16384*768 (reused as P)
    float* A0  = h + (size_t)NB * NG * NH;            // 16384*512
    float* u   = A0 + (size_t)NB * NG * NG;           // 16384
    float* v   = u + NB * NG;                         // 16384
    float* pm  = v + NB * NG;                         // 32*8*512 (unused)
    float* ps  = pm + NB * 8 * NG;                    // 32*8*512
    int* rbCr  = (int*)(ps + NB * 8 * NG);            // 16384
    int* rbCc  = rbCr + NB * NG;                      // 16384
    unsigned long long* freeRow = (unsigned long long*)(rbCc + NB * NG); // 256
    unsigned long long* freeCol = freeRow + NB * 8;   // 256
    int* remaining = (int*)(freeCol + NB * 8);        // 32
    int* permInt   = remaining + 32;                  // 16384

    const int M = NB * NG;  // 16384

    // h = relu(feats @ W1 + b1)   [bf16x3 split MFMA, 6 products]
    gemm_bias_mfma<<<dim3((M / 128) * (NH / 128)), 256, 0, stream>>>(
        feats, W1, b1, h, M, NH, NC, 0);
    // A0 = (h @ W2 + b2) / TAU    [bf16x3 split MFMA, 6 products]
    gemm_bias_mfma<<<dim3((M / 128) * (NG / 128)), 256, 0, stream>>>(
        h, W2, b2, A0, M, NG, NH, 1);

    hipMemsetAsync(v, 0, (size_t)NB * NG * sizeof(float), stream);

    for (int it = 0; it < 10; ++it) {
        sinkhorn_iter<<<dim3(NB * 8), 256, 0, stream>>>(A0, u, v, ps);
        col_combine_lin<<<dim3(M / 256), 256, 0, stream>>>(ps, v);
    }

    float* P = h;
    p_rowmax<<<dim3(M / 4), 256, 0, stream>>>(A0, u, v, P, rbCr, rbCc,
                                              freeRow, freeCol, remaining);

    for (int r = 0; r < 6; ++r)
        mutual_round<<<dim3(NB), 512, 0, stream>>>(P, rbCr, rbCc, freeRow,
                                                   freeCol, remaining, permInt);

    greedy_cleanup<<<dim3(NB), 64, 0, stream>>>(P, freeRow, freeCol,
                                                remaining, permInt);

    scatter_all<<<dim3((NB * NG * 96) / 256), 256, 0, stream>>>(
        coords, feats, permInt, outCoords, outFeats, outPerm);
}

// Round 15
// 392.148 us; speedup vs baseline: 1.4072x; 1.0204x over previous
//
#include <hip/hip_runtime.h>
#include <math.h>

#define NB 32
#define NG 512
#define NC 384
#define NH 768

typedef float f32x4v __attribute__((ext_vector_type(4)));
typedef __bf16 bf16_t;
typedef bf16_t bf16x8 __attribute__((ext_vector_type(8)));
typedef bf16_t bf16x4 __attribute__((ext_vector_type(4)));

#define LDSK 40   // 32 k (permuted) + 8 pad; row stride 80 B (16B-aligned)

__device__ __forceinline__ void split3(float x, bf16_t& h, bf16_t& m, bf16_t& lo)
{
    h = (bf16_t)x;
    float r1 = x - (float)h;
    m = (bf16_t)r1;
    float r2 = r1 - (float)m;
    lo = (bf16_t)r2;
}

// ---------------- GEMM via bf16 MFMA, exact 3-way split, 6 products
// (hh,hm,mh,mm,hl,lh). Register-blocked fragments (24 ds_read_b128/chunk,
// 96 MFMAs from regs). SOFTWARE-PIPELINED global loads: chunk kc+1's raw
// data is fetched into registers right after the LDS-write barrier, hiding
// ~500cy HBM/L2 latency under frag reads + MFMA (round-14 theory: staging
// loads were consumed immediately by split3 -> latency fully exposed).
// 128x128 tile, 4 waves (2x2 of 64x64), K-chunk 32. LDS k-dim PERMUTED:
// pos(k) = ((k>>2)&3)*8 + (k>>4)*4 + (k&3) so each fragment is contiguous.
// mode 0: relu, mode 1: /0.1 (scores/TAU). Deterministic fixed order.
__global__ __launch_bounds__(256, 2) void gemm_bias_mfma(
    const float* __restrict__ A, const float* __restrict__ Bw,
    const float* __restrict__ bias, float* __restrict__ Co,
    int M, int N, int K, int mode)
{
    __shared__ __align__(16) bf16_t sA[3][128][LDSK];
    __shared__ __align__(16) bf16_t sB[3][128][LDSK];   // B^T: [col][k-pos]
    int ntiles = N >> 7;
    int bm = (blockIdx.x / ntiles) << 7;
    int bn = (blockIdx.x % ntiles) << 7;
    int t = threadIdx.x;
    int l = t & 63;
    int w = t >> 6;
    int wr = (w >> 1) << 6;       // wave row base (0/64)
    int wc = (w & 1) << 6;        // wave col base (0/64)
    int fr = l & 15;              // frag row/col
    int fk = (l >> 4) << 3;       // frag k-pos base (0,8,16,24)

    // staging: A: thread -> (row = t>>1, khalf = (t&1)*16)
    int sa_row = t >> 1;
    int sa_kh = (t & 1) << 4;
    int hsel = (sa_kh >> 4) << 2;      // 0 or 4
    // staging: B: thread -> (k quad = (t&7)*4, col quad = (t>>3)*4)
    int sb_k = (t & 7) << 2;
    int sb_n = (t >> 3) << 2;
    int bcol = ((sb_k >> 2) & 3) * 8 + ((sb_k >> 4) << 2);

    const float* apBase = A + (size_t)(bm + sa_row) * K + sa_kh;

    f32x4v acc[4][4];
#pragma unroll
    for (int i = 0; i < 4; i++)
#pragma unroll
        for (int j = 0; j < 4; j++) acc[i][j] = (f32x4v)(0.f);

    // prefetch chunk 0 raw data into registers
    float4 q0 = *(const float4*)(apBase + 0);
    float4 q1 = *(const float4*)(apBase + 4);
    float4 q2 = *(const float4*)(apBase + 8);
    float4 q3 = *(const float4*)(apBase + 12);
    float4 bq0 = *(const float4*)(Bw + (size_t)(sb_k + 0) * N + bn + sb_n);
    float4 bq1 = *(const float4*)(Bw + (size_t)(sb_k + 1) * N + bn + sb_n);
    float4 bq2 = *(const float4*)(Bw + (size_t)(sb_k + 2) * N + bn + sb_n);
    float4 bq3 = *(const float4*)(Bw + (size_t)(sb_k + 3) * N + bn + sb_n);

    for (int kc = 0; kc < K; kc += 32) {
        __syncthreads();   // all waves done reading previous chunk's fragments
        // ---- split current chunk (from regs) into LDS ----
        {
            float xs[16] = { q0.x, q0.y, q0.z, q0.w, q1.x, q1.y, q1.z, q1.w,
                             q2.x, q2.y, q2.z, q2.w, q3.x, q3.y, q3.z, q3.w };
            bf16_t hs[16], ms[16], ls[16];
#pragma unroll
            for (int e = 0; e < 16; e++) split3(xs[e], hs[e], ms[e], ls[e]);
#pragma unroll
            for (int qd = 0; qd < 4; qd++) {
                int col = qd * 8 + hsel;
                *(bf16x4*)&sA[0][sa_row][col] =
                    (bf16x4){ hs[4 * qd], hs[4 * qd + 1], hs[4 * qd + 2], hs[4 * qd + 3] };
                *(bf16x4*)&sA[1][sa_row][col] =
                    (bf16x4){ ms[4 * qd], ms[4 * qd + 1], ms[4 * qd + 2], ms[4 * qd + 3] };
                *(bf16x4*)&sA[2][sa_row][col] =
                    (bf16x4){ ls[4 * qd], ls[4 * qd + 1], ls[4 * qd + 2], ls[4 * qd + 3] };
            }
            float bbv[4][4] = {
                { bq0.x, bq0.y, bq0.z, bq0.w },
                { bq1.x, bq1.y, bq1.z, bq1.w },
                { bq2.x, bq2.y, bq2.z, bq2.w },
                { bq3.x, bq3.y, bq3.z, bq3.w } };
#pragma unroll
            for (int n = 0; n < 4; n++) {
                bf16_t hb[4], mb[4], lb[4];
#pragma unroll
                for (int kk = 0; kk < 4; kk++) split3(bbv[kk][n], hb[kk], mb[kk], lb[kk]);
                *(bf16x4*)&sB[0][sb_n + n][bcol] = (bf16x4){ hb[0], hb[1], hb[2], hb[3] };
                *(bf16x4*)&sB[1][sb_n + n][bcol] = (bf16x4){ mb[0], mb[1], mb[2], mb[3] };
                *(bf16x4*)&sB[2][sb_n + n][bcol] = (bf16x4){ lb[0], lb[1], lb[2], lb[3] };
            }
        }
        __syncthreads();   // LDS ready
        // ---- issue next chunk's global loads; latency hides under MFMA ----
        if (kc + 32 < K) {
            const float* ap = apBase + kc + 32;
            q0 = *(const float4*)(ap + 0);
            q1 = *(const float4*)(ap + 4);
            q2 = *(const float4*)(ap + 8);
            q3 = *(const float4*)(ap + 12);
            const float* bp = Bw + (size_t)(kc + 32 + sb_k) * N + bn + sb_n;
            bq0 = *(const float4*)(bp + 0 * N);
            bq1 = *(const float4*)(bp + 1 * N);
            bq2 = *(const float4*)(bp + 2 * N);
            bq3 = *(const float4*)(bp + 3 * N);
        }
        // ---- load all fragments once (24 x ds_read_b128), then 96 MFMAs ----
        bf16x8 afH[4], afM[4], afL[4], bfH[4], bfM[4], bfL[4];
#pragma unroll
        for (int i = 0; i < 4; i++) {
            afH[i] = *(const bf16x8*)&sA[0][wr + i * 16 + fr][fk];
            afM[i] = *(const bf16x8*)&sA[1][wr + i * 16 + fr][fk];
            afL[i] = *(const bf16x8*)&sA[2][wr + i * 16 + fr][fk];
            bfH[i] = *(const bf16x8*)&sB[0][wc + i * 16 + fr][fk];
            bfM[i] = *(const bf16x8*)&sB[1][wc + i * 16 + fr][fk];
            bfL[i] = *(const bf16x8*)&sB[2][wc + i * 16 + fr][fk];
        }
        // per-accumulator product order: hh, hm, mh, mm, hl, lh
#pragma unroll
        for (int i = 0; i < 4; i++)
#pragma unroll
            for (int j = 0; j < 4; j++) {
                acc[i][j] = __builtin_amdgcn_mfma_f32_16x16x32_bf16(
                    afH[i], bfH[j], acc[i][j], 0, 0, 0);
                acc[i][j] = __builtin_amdgcn_mfma_f32_16x16x32_bf16(
                    afH[i], bfM[j], acc[i][j], 0, 0, 0);
                acc[i][j] = __builtin_amdgcn_mfma_f32_16x16x32_bf16(
                    afM[i], bfH[j], acc[i][j], 0, 0, 0);
                acc[i][j] = __builtin_amdgcn_mfma_f32_16x16x32_bf16(
                    afM[i], bfM[j], acc[i][j], 0, 0, 0);
                acc[i][j] = __builtin_amdgcn_mfma_f32_16x16x32_bf16(
                    afH[i], bfL[j], acc[i][j], 0, 0, 0);
                acc[i][j] = __builtin_amdgcn_mfma_f32_16x16x32_bf16(
                    afL[i], bfH[j], acc[i][j], 0, 0, 0);
            }
    }

    // ---- epilogue: C/D layout col = l&15, row = (l>>4)*4 + reg (m89) ----
    int orow = (l >> 4) << 2;
#pragma unroll
    for (int j = 0; j < 4; j++) {
        int colg = bn + wc + j * 16 + fr;
        float bj = bias[colg];
#pragma unroll
        for (int i = 0; i < 4; i++) {
            int rowg = bm + wr + i * 16 + orow;
#pragma unroll
            for (int r = 0; r < 4; r++) {
                float val = acc[i][j][r] + bj;
                val = (mode == 0) ? fmaxf(val, 0.f) : val / 0.1f;
                Co[(size_t)(rowg + r) * N + colg] = val;
            }
        }
    }
}

// ======== DPP reduce networks to lane 63 (pure VALU) ========
#define DPP6_MAXF(x)                                                              \
    { int _t;                                                                     \
      _t = __builtin_amdgcn_update_dpp(__float_as_int(x), __float_as_int(x),      \
               0x111, 0xf, 0xf, false); x = fmaxf(x, __int_as_float(_t));         \
      _t = __builtin_amdgcn_update_dpp(__float_as_int(x), __float_as_int(x),      \
               0x112, 0xf, 0xf, false); x = fmaxf(x, __int_as_float(_t));         \
      _t = __builtin_amdgcn_update_dpp(__float_as_int(x), __float_as_int(x),      \
               0x114, 0xf, 0xf, false); x = fmaxf(x, __int_as_float(_t));         \
      _t = __builtin_amdgcn_update_dpp(__float_as_int(x), __float_as_int(x),      \
               0x118, 0xf, 0xf, false); x = fmaxf(x, __int_as_float(_t));         \
      _t = __builtin_amdgcn_update_dpp(__float_as_int(x), __float_as_int(x),      \
               0x142, 0xa, 0xf, false); x = fmaxf(x, __int_as_float(_t));         \
      _t = __builtin_amdgcn_update_dpp(__float_as_int(x), __float_as_int(x),      \
               0x143, 0xc, 0xf, false); x = fmaxf(x, __int_as_float(_t)); }

#define DPP6_ADDF(x)                                                              \
    { int _t;                                                                     \
      _t = __builtin_amdgcn_update_dpp(__float_as_int(x), __float_as_int(x),      \
               0x111, 0xf, 0xf, false); x = x + __int_as_float(_t);               \
      _t = __builtin_amdgcn_update_dpp(__float_as_int(x), __float_as_int(x),      \
               0x112, 0xf, 0xf, false); x = x + __int_as_float(_t);               \
      _t = __builtin_amdgcn_update_dpp(__float_as_int(x), __float_as_int(x),      \
               0x114, 0xf, 0xf, false); x = x + __int_as_float(_t);               \
      _t = __builtin_amdgcn_update_dpp(__float_as_int(x), __float_as_int(x),      \
               0x118, 0xf, 0xf, false); x = x + __int_as_float(_t);               \
      _t = __builtin_amdgcn_update_dpp(__float_as_int(x), __float_as_int(x),      \
               0x142, 0xa, 0xf, false); x = x + __int_as_float(_t);               \
      _t = __builtin_amdgcn_update_dpp(__float_as_int(x), __float_as_int(x),      \
               0x143, 0xc, 0xf, false); x = x + __int_as_float(_t); }

// ---------------- Fused Sinkhorn half-iterations (round-9 design).
__global__ __launch_bounds__(256) void sinkhorn_iter(
    const float* __restrict__ A0, float* __restrict__ uu,
    const float* __restrict__ vv, float* __restrict__ ps)
{
    int blk = blockIdx.x;          // NB*8
    int b = blk >> 3, rc = blk & 7;
    int t = threadIdx.x;
    int l = t & 63, w = t >> 6;
    const float* vb = vv + (b << 9);
    float4 v0 = *(const float4*)(vb + 4 * l);
    float4 v1 = *(const float4*)(vb + 256 + 4 * l);
    int row0 = (rc << 6) + (w << 4);
    const float* base = A0 + ((size_t)((b << 9) + row0) << 9);

    float cs0 = 0.f, cs1 = 0.f, cs2 = 0.f, cs3 = 0.f;
    float cs4 = 0.f, cs5 = 0.f, cs6 = 0.f, cs7 = 0.f;

    for (int rr = 0; rr < 16; ++rr) {
        const float* rowp = base + ((size_t)rr << 9);
        float4 a0 = *(const float4*)(rowp + 4 * l);
        float4 a1 = *(const float4*)(rowp + 256 + 4 * l);
        float x0 = a0.x + v0.x, x1 = a0.y + v0.y;
        float x2 = a0.z + v0.z, x3 = a0.w + v0.w;
        float x4 = a1.x + v1.x, x5 = a1.y + v1.y;
        float x6 = a1.z + v1.z, x7 = a1.w + v1.w;
        float m = fmaxf(fmaxf(fmaxf(x0, x1), fmaxf(x2, x3)),
                        fmaxf(fmaxf(x4, x5), fmaxf(x6, x7)));
        DPP6_MAXF(m)
        int mi = __builtin_amdgcn_readlane(__float_as_int(m), 63);
        m = __int_as_float(mi);
        float e0 = __expf(x0 - m), e1 = __expf(x1 - m);
        float e2 = __expf(x2 - m), e3 = __expf(x3 - m);
        float e4 = __expf(x4 - m), e5 = __expf(x5 - m);
        float e6 = __expf(x6 - m), e7 = __expf(x7 - m);
        float s = ((e0 + e1) + (e2 + e3)) + ((e4 + e5) + (e6 + e7));
        DPP6_ADDF(s)
        int si = __builtin_amdgcn_readlane(__float_as_int(s), 63);
        s = __int_as_float(si);
        float inv = 1.0f / s;
        cs0 += e0 * inv; cs1 += e1 * inv; cs2 += e2 * inv; cs3 += e3 * inv;
        cs4 += e4 * inv; cs5 += e5 * inv; cs6 += e6 * inv; cs7 += e7 * inv;
        if (l == 63) uu[(b << 9) + row0 + rr] = -(m + __logf(s));
    }

    __shared__ float sacc[4][512];
    float4 w0; w0.x = cs0; w0.y = cs1; w0.z = cs2; w0.w = cs3;
    float4 w1; w1.x = cs4; w1.y = cs5; w1.z = cs6; w1.w = cs7;
    *(float4*)&sacc[w][4 * l] = w0;
    *(float4*)&sacc[w][256 + 4 * l] = w1;
    __syncthreads();
    float pA = sacc[0][t] + sacc[1][t] + sacc[2][t] + sacc[3][t];
    float pB = sacc[0][256 + t] + sacc[1][256 + t] + sacc[2][256 + t] + sacc[3][256 + t];
    int o = ((b << 3) + rc) * NG;
    ps[o + t] = pA;
    ps[o + 256 + t] = pB;
}

// ---------------- combine 8 linear partials -> v' = v - log(colsum)
__global__ __launch_bounds__(256) void col_combine_lin(
    const float* __restrict__ ps, float* __restrict__ vv)
{
    int tid = blockIdx.x * 256 + threadIdx.x;  // NB*NG
    int b = tid >> 9, j = tid & 511;
    float S = 0.f;
#pragma unroll
    for (int rc = 0; rc < 8; rc++) S += ps[((b << 3) + rc) * NG + j];
    vv[tid] = vv[tid] - __logf(S);
}

// wave-cooperative masked row argmax over cols 8l..8l+7 per lane.
__device__ __forceinline__ void masked_row_argmax(
    const float* __restrict__ rowp, int l, unsigned int free8, int rr,
    float& outV, int& outF)
{
    float4 x0 = *(const float4*)(rowp + 8 * l);
    float4 x1 = *(const float4*)(rowp + 8 * l + 4);
    float q0 = (free8 & 1u)   ? x0.x : -1.0f;
    float q1 = (free8 & 2u)   ? x0.y : -1.0f;
    float q2 = (free8 & 4u)   ? x0.z : -1.0f;
    float q3 = (free8 & 8u)   ? x0.w : -1.0f;
    float q4 = (free8 & 16u)  ? x1.x : -1.0f;
    float q5 = (free8 & 32u)  ? x1.y : -1.0f;
    float q6 = (free8 & 64u)  ? x1.z : -1.0f;
    float q7 = (free8 & 128u) ? x1.w : -1.0f;
    float lm = fmaxf(fmaxf(fmaxf(q0, q1), fmaxf(q2, q3)),
                     fmaxf(fmaxf(q4, q5), fmaxf(q6, q7)));
    int sb = (rr << 9) + 8 * l;
    int lf = 0x7FFFFFFF;
    lf = (q7 == lm) ? sb + 7 : lf;
    lf = (q6 == lm) ? sb + 6 : lf;
    lf = (q5 == lm) ? sb + 5 : lf;
    lf = (q4 == lm) ? sb + 4 : lf;
    lf = (q3 == lm) ? sb + 3 : lf;
    lf = (q2 == lm) ? sb + 2 : lf;
    lf = (q1 == lm) ? sb + 1 : lf;
    lf = (q0 == lm) ? sb + 0 : lf;
    float gg = lm;
    DPP6_MAXF(gg)
    int ggi = __builtin_amdgcn_readlane(__float_as_int(gg), 63);
    float g1 = __int_as_float(ggi);
    unsigned long long tb = __ballot(lm == g1);
    int tl = __ffsll(tb) - 1;
    outV = g1;
    outF = __builtin_amdgcn_readlane(lf, tl);
}

// ---------------- P = exp((A0+u)+v) (libm expf) + per-row argmax + state init.
__global__ __launch_bounds__(256) void p_rowmax(
    const float* __restrict__ A0, const float* __restrict__ uu,
    const float* __restrict__ vv, float* __restrict__ P,
    int* __restrict__ rbCr, int* __restrict__ rbCc,
    unsigned long long* __restrict__ freeRow,
    unsigned long long* __restrict__ freeCol,
    int* __restrict__ remaining)
{
    if (blockIdx.x == 0) {
        int t = threadIdx.x;
        freeRow[t] = ~0ULL;
        freeCol[t] = ~0ULL;
        if (t < NB) remaining[t] = NG;
    }
    int wrow = blockIdx.x * 4 + (threadIdx.x >> 6);
    int l = threadIdx.x & 63;
    int b = wrow >> 9;
    float ur = uu[wrow];
    const float* vb = vv + (b << 9);
    size_t ro = (size_t)wrow << 9;
    float4 a0 = *(const float4*)(A0 + ro + 8 * l);
    float4 a1 = *(const float4*)(A0 + ro + 8 * l + 4);
    float4 v0 = *(const float4*)(vb + 8 * l);
    float4 v1 = *(const float4*)(vb + 8 * l + 4);
    float p0 = expf(a0.x + ur + v0.x);
    float p1 = expf(a0.y + ur + v0.y);
    float p2 = expf(a0.z + ur + v0.z);
    float p3 = expf(a0.w + ur + v0.w);
    float p4 = expf(a1.x + ur + v1.x);
    float p5 = expf(a1.y + ur + v1.y);
    float p6 = expf(a1.z + ur + v1.z);
    float p7 = expf(a1.w + ur + v1.w);
    float4 o0; o0.x = p0; o0.y = p1; o0.z = p2; o0.w = p3;
    float4 o1; o1.x = p4; o1.y = p5; o1.z = p6; o1.w = p7;
    *(float4*)(P + ro + 8 * l) = o0;
    *(float4*)(P + ro + 8 * l + 4) = o1;
    float mv = fmaxf(fmaxf(fmaxf(p0, p1), fmaxf(p2, p3)),
                     fmaxf(fmaxf(p4, p5), fmaxf(p6, p7)));
    int cb = 8 * l;
    int f = 0x7FFFFFFF;
    f = (p7 == mv) ? cb + 7 : f;
    f = (p6 == mv) ? cb + 6 : f;
    f = (p5 == mv) ? cb + 5 : f;
    f = (p4 == mv) ? cb + 4 : f;
    f = (p3 == mv) ? cb + 3 : f;
    f = (p2 == mv) ? cb + 2 : f;
    f = (p1 == mv) ? cb + 1 : f;
    f = (p0 == mv) ? cb + 0 : f;
    float g = mv;
    DPP6_MAXF(g)
    int gi = __builtin_amdgcn_readlane(__float_as_int(g), 63);
    float gm = __int_as_float(gi);
    unsigned long long tb = __ballot(mv == gm);
    int tl = __ffsll(tb) - 1;
    int bestc = __builtin_amdgcn_readlane(f, tl);
    if (l == 0) { rbCr[wrow] = bestc; rbCc[wrow] = -1; }
}

// ---------------- One parallel mutual-max round (exact greedy equivalence).
__global__ __launch_bounds__(512) void mutual_round(
    const float* __restrict__ P, int* __restrict__ rbCr, int* __restrict__ rbCc,
    unsigned long long* __restrict__ freeRow,
    unsigned long long* __restrict__ freeCol,
    int* __restrict__ remaining, int* __restrict__ permInt)
{
    int b = blockIdx.x;
    if (remaining[b] == 0) return;
    int t = threadIdx.x;
    int l = t & 63;
    int w = t >> 6;
    const float* Pb = P + (size_t)b * NG * NG;

    __shared__ unsigned int fr[16], fc[16];
    __shared__ int sRC[NG];
    __shared__ int sCC[NG];
    __shared__ int freeList[NG];
    __shared__ int dirtyRows[NG];
    __shared__ int nFree, nDirtyRow, takeCnt;
    __shared__ int wCnt[8], wOff[8];

    if (t < 8) {
        unsigned long long x = freeRow[b * 8 + t];
        fr[2 * t] = (unsigned)x; fr[2 * t + 1] = (unsigned)(x >> 32);
    } else if (t < 16) {
        int i = t - 8;
        unsigned long long x = freeCol[b * 8 + i];
        fc[2 * i] = (unsigned)x; fc[2 * i + 1] = (unsigned)(x >> 32);
    }
    sRC[t] = rbCr[(b << 9) + t];
    sCC[t] = rbCc[(b << 9) + t];
    if (t == 0) { nDirtyRow = 0; takeCnt = 0; }
    __syncthreads();

    bool isFree = (fr[t >> 5] >> (t & 31)) & 1u;
    unsigned long long bm = __ballot(isFree);
    if (l == 0) wCnt[w] = __popcll(bm);
    if (isFree) {
        int c = sRC[t];
        if (!((fc[c >> 5] >> (c & 31)) & 1u)) {
            int d = atomicAdd(&nDirtyRow, 1);
            dirtyRows[d] = t;
        }
    }
    __syncthreads();
    if (t == 0) {
        int s = 0;
#pragma unroll
        for (int i = 0; i < 8; i++) { wOff[i] = s; s += wCnt[i]; }
        nFree = s;
    }
    __syncthreads();
    if (isFree) {
        int rank = __popcll(bm & ((1ULL << l) - 1ULL));
        freeList[wOff[w] + rank] = t;
    }
    __syncthreads();

    int nd = nDirtyRow;
    for (int d = w; d < nd; d += 8) {
        int r = dirtyRows[d];
        unsigned int free8 = (fc[l >> 2] >> ((l & 3) * 8)) & 0xFFu;
        float nv; int nf;
        masked_row_argmax(Pb + ((size_t)r << 9), l, free8, r, nv, nf);
        if (l == 0) {
            int c = nf & 511;
            sRC[r] = c;
            rbCr[(b << 9) + r] = c;
        }
    }
    __syncthreads();

    bool colFree = (fc[t >> 5] >> (t & 31)) & 1u;
    int cachedR = sCC[t];
    bool colDirty = colFree &&
        (cachedR < 0 || !((fr[cachedR >> 5] >> (cachedR & 31)) & 1u));
    if (colDirty) {
        float best = -1.f; int bestr = 0x7FFFFFFF;
        int nf2 = nFree;
        int i = 0;
        for (; i + 4 <= nf2; i += 4) {
            int r0 = freeList[i], r1 = freeList[i + 1];
            int r2 = freeList[i + 2], r3 = freeList[i + 3];
            float v0 = Pb[((size_t)r0 << 9) + t];
            float v1 = Pb[((size_t)r1 << 9) + t];
            float v2 = Pb[((size_t)r2 << 9) + t];
            float v3 = Pb[((size_t)r3 << 9) + t];
            if (v0 > best) { best = v0; bestr = r0; }
            if (v1 > best) { best = v1; bestr = r1; }
            if (v2 > best) { best = v2; bestr = r2; }
            if (v3 > best) { best = v3; bestr = r3; }
        }
        for (; i < nf2; ++i) {
            int ri = freeList[i];
            float vv2 = Pb[((size_t)ri << 9) + t];
            if (vv2 > best) { best = vv2; bestr = ri; }
        }
        sCC[t] = bestr;
        rbCc[(b << 9) + t] = bestr;
    }
    __syncthreads();

    if (colFree) {
        int r = sCC[t];
        if (r >= 0 && r < NG && sRC[r] == t) {
            permInt[(b << 9) + r] = t;
            atomicAnd(&fr[r >> 5], ~(1u << (r & 31)));
            atomicAnd(&fc[t >> 5], ~(1u << (t & 31)));
            atomicAdd(&takeCnt, 1);
        }
    }
    __syncthreads();
    if (t < 8) {
        freeRow[b * 8 + t] =
            ((unsigned long long)fr[2 * t + 1] << 32) | fr[2 * t];
    } else if (t < 16) {
        int i = t - 8;
        freeCol[b * 8 + i] =
            ((unsigned long long)fc[2 * i + 1] << 32) | fc[2 * i];
    }
    if (t == 0) remaining[b] = remaining[b] - takeCnt;
}

// ---------------- Exact sequential cleanup (rarely does work).
__global__ __launch_bounds__(64) void greedy_cleanup(
    const float* __restrict__ P,
    const unsigned long long* __restrict__ freeRow,
    const unsigned long long* __restrict__ freeCol,
    const int* __restrict__ remaining, int* __restrict__ permInt)
{
    int b = blockIdx.x;
    if (remaining[b] == 0) return;
    int l = threadIdx.x;
    const float* Pb = P + (size_t)b * NG * NG;

    unsigned long long wR = freeRow[b * 8 + (l >> 3)];
    unsigned int myRows = (unsigned int)((wR >> ((l & 7) * 8)) & 0xFF);
    unsigned long long wC = freeCol[b * 8 + (l >> 3)];
    unsigned int free8 = (unsigned int)((wC >> ((l & 7) * 8)) & 0xFF);

    float rv[8]; int rf[8];
#pragma unroll
    for (int k = 0; k < 8; k++) { rv[k] = -1.f; rf[k] = 0x7FFFFFFF; }

    int dmk = (int)myRows;
    unsigned long long act = __ballot(dmk != 0);
    while (act) {
        int src = __ffsll(act) - 1;
        int kk = __ffs(__builtin_amdgcn_readlane(dmk, src)) - 1;
        if (l == src) dmk &= ~(1 << kk);
        int rr = (src << 3) + kk;
        float nv; int nf;
        masked_row_argmax(Pb + ((size_t)rr << 9), l, free8, rr, nv, nf);
        bool upd = (l == src);
        rv[0] = (upd && kk == 0) ? nv : rv[0]; rf[0] = (upd && kk == 0) ? nf : rf[0];
        rv[1] = (upd && kk == 1) ? nv : rv[1]; rf[1] = (upd && kk == 1) ? nf : rf[1];
        rv[2] = (upd && kk == 2) ? nv : rv[2]; rf[2] = (upd && kk == 2) ? nf : rf[2];
        rv[3] = (upd && kk == 3) ? nv : rv[3]; rf[3] = (upd && kk == 3) ? nf : rf[3];
        rv[4] = (upd && kk == 4) ? nv : rv[4]; rf[4] = (upd && kk == 4) ? nf : rf[4];
        rv[5] = (upd && kk == 5) ? nv : rv[5]; rf[5] = (upd && kk == 5) ? nf : rf[5];
        rv[6] = (upd && kk == 6) ? nv : rv[6]; rf[6] = (upd && kk == 6) ? nf : rf[6];
        rv[7] = (upd && kk == 7) ? nv : rv[7]; rf[7] = (upd && kk == 7) ? nf : rf[7];
        act = __ballot(dmk != 0);
    }

    for (int step = 0; step < NG; ++step) {
        float mv = fmaxf(fmaxf(fmaxf(rv[0], rv[1]), fmaxf(rv[2], rv[3])),
                         fmaxf(fmaxf(rv[4], rv[5]), fmaxf(rv[6], rv[7])));
        int f = 0x7FFFFFFF;
        f = (rv[7] == mv) ? rf[7] : f;
        f = (rv[6] == mv) ? rf[6] : f;
        f = (rv[5] == mv) ? rf[5] : f;
        f = (rv[4] == mv) ? rf[4] : f;
        f = (rv[3] == mv) ? rf[3] : f;
        f = (rv[2] == mv) ? rf[2] : f;
        f = (rv[1] == mv) ? rf[1] : f;
        f = (rv[0] == mv) ? rf[0] : f;
        float g = mv;
        DPP6_MAXF(g)
        int gi = __builtin_amdgcn_readlane(__float_as_int(g), 63);
        float gm = __int_as_float(gi);
        if (gm < 0.f) break;
        unsigned long long tb = __ballot(mv == gm);
        int tl = __ffsll(tb) - 1;
        int bestf = __builtin_amdgcn_readlane(f, tl);
        int r = bestf >> 9, c = bestf & 511;
        if (l == 0) permInt[(b << 9) + r] = c;
        if (l == (c >> 3)) free8 &= ~(1u << (c & 7));
        int rl = r - (l << 3);
        int dm2 = 0;
#pragma unroll
        for (int k = 0; k < 8; k++) {
            bool alive = rv[k] >= 0.f;
            bool cm = ((rf[k] ^ c) & 511) == 0;
            bool taken = (rl == k);
            if (taken) rv[k] = -1.f;
            dm2 |= (alive && cm && !taken) ? (1 << k) : 0;
        }
        unsigned long long act2 = __ballot(dm2 != 0);
        while (act2) {
            int src = __ffsll(act2) - 1;
            int kk = __ffs(__builtin_amdgcn_readlane(dm2, src)) - 1;
            if (l == src) dm2 &= ~(1 << kk);
            int rr = (src << 3) + kk;
            float nv; int nf;
            masked_row_argmax(Pb + ((size_t)rr << 9), l, free8, rr, nv, nf);
            bool upd = (l == src);
            rv[0] = (upd && kk == 0) ? nv : rv[0]; rf[0] = (upd && kk == 0) ? nf : rf[0];
            rv[1] = (upd && kk == 1) ? nv : rv[1]; rf[1] = (upd && kk == 1) ? nf : rf[1];
            rv[2] = (upd && kk == 2) ? nv : rv[2]; rf[2] = (upd && kk == 2) ? nf : rf[2];
            rv[3] = (upd && kk == 3) ? nv : rv[3]; rf[3] = (upd && kk == 3) ? nf : rf[3];
            rv[4] = (upd && kk == 4) ? nv : rv[4]; rf[4] = (upd && kk == 4) ? nf : rf[4];
            rv[5] = (upd && kk == 5) ? nv : rv[5]; rf[5] = (upd && kk == 5) ? nf : rf[5];
            rv[6] = (upd && kk == 6) ? nv : rv[6]; rf[6] = (upd && kk == 6) ? nf : rf[6];
            rv[7] = (upd && kk == 7) ? nv : rv[7]; rf[7] = (upd && kk == 7) ? nf : rf[7];
            act2 = __ballot(dm2 != 0);
        }
    }
}

// ---------------- apply permutation (coords + feats + perm float, fused)
__global__ void scatter_all(const float* __restrict__ coords,
    const float* __restrict__ feats, const int* __restrict__ perm,
    float* __restrict__ dstCoords, float* __restrict__ dstFeats,
    float* __restrict__ permF)
{
    int tid = blockIdx.x * 256 + threadIdx.x;   // NB*NG*96 float4s
    int rc = tid / 96;
    int q = tid - rc * 96;
    int b = rc >> 9;
    int p = perm[rc];
    const float4* s4 = (const float4*)(feats + (size_t)rc * NC);
    float4* d4 = (float4*)(dstFeats + ((size_t)(b << 9) + p) * NC);
    d4[q] = s4[q];
    if (q == 0) {
        permF[rc] = (float)p;
        size_t so = (size_t)rc * 3;
        size_t dd = ((size_t)(b << 9) + p) * 3;
        dstCoords[dd] = coords[so];
        dstCoords[dd + 1] = coords[so + 1];
        dstCoords[dd + 2] = coords[so + 2];
    }
}

extern "C" void kernel_launch(void* const* d_in, const int* in_sizes, int n_in,
                              void* d_out, int out_size, void* d_ws, size_t ws_size,
                              hipStream_t stream)
{
    const float* coords = (const float*)d_in[0];
    const float* feats  = (const float*)d_in[1];
    const float* W1 = (const float*)d_in[2];
    const float* b1 = (const float*)d_in[3];
    const float* W2 = (const float*)d_in[4];
    const float* b2 = (const float*)d_in[5];

    float* out = (float*)d_out;
    float* outCoords = out;
    float* outFeats  = out + (size_t)NB * NG * 3;
    float* outPerm   = out + (size_t)NB * NG * 3 + (size_t)NB * NG * NC;

    float* ws = (float*)d_ws;
    float* h   = ws;                                  // 16384*768 (reused as P)
    float* A0  = h + (size_t)NB * NG * NH;            // 16384*512
    float* u   = A0 + (size_t)NB * NG * NG;           // 16384
    float* v   = u + NB * NG;                         // 16384
    float* pm  = v + NB * NG;                         // 32*8*512 (unused)
    float* ps  = pm + NB * 8 * NG;                    // 32*8*512
    int* rbCr  = (int*)(ps + NB * 8 * NG);            // 16384
    int* rbCc  = rbCr + NB * NG;                      // 16384
    unsigned long long* freeRow = (unsigned long long*)(rbCc + NB * NG); // 256
    unsigned long long* freeCol = freeRow + NB * 8;   // 256
    int* remaining = (int*)(freeCol + NB * 8);        // 32
    int* permInt   = remaining + 32;                  // 16384

    const int M = NB * NG;  // 16384

    // h = relu(feats @ W1 + b1)   [bf16x3 split MFMA, 6 products, pipelined]
    gemm_bias_mfma<<<dim3((M / 128) * (NH / 128)), 256, 0, stream>>>(
        feats, W1, b1, h, M, NH, NC, 0);
    // A0 = (h @ W2 + b2) / TAU    [bf16x3 split MFMA, 6 products, pipelined]
    gemm_bias_mfma<<<dim3((M / 128) * (NG / 128)), 256, 0, stream>>>(
        h, W2, b2, A0, M, NG, NH, 1);

    hipMemsetAsync(v, 0, (size_t)NB * NG * sizeof(float), stream);

    for (int it = 0; it < 10; ++it) {
        sinkhorn_iter<<<dim3(NB * 8), 256, 0, stream>>>(A0, u, v, ps);
        col_combine_lin<<<dim3(M / 256), 256, 0, stream>>>(ps, v);
    }

    float* P = h;
    p_rowmax<<<dim3(M / 4), 256, 0, stream>>>(A0, u, v, P, rbCr, rbCc,
                                              freeRow, freeCol, remaining);

    for (int r = 0; r < 6; ++r)
        mutual_round<<<dim3(NB), 512, 0, stream>>>(P, rbCr, rbCc, freeRow,
                                                   freeCol, remaining, permInt);

    greedy_cleanup<<<dim3(NB), 64, 0, stream>>>(P, freeRow, freeCol,
                                                remaining, permInt);

    scatter_all<<<dim3((NB * NG * 96) / 256), 256, 0, stream>>>(
        coords, feats, permInt, outCoords, outFeats, outPerm);
}